// Round 5
// baseline (2106.772 us; speedup 1.0000x reference)
//
#include <hip/hip_runtime.h>
#include <hip/hip_bf16.h>

// Bidirectional GRU (Keras reset_after=True) + dense classifier.
// B=32, T=160, D=512, H=256, C=6625.
// Round 5: revert R4's cross-WG scan (sync RTT >> L2 restream). Streaming
//   scan v4: uint4 weight loads (4x fewer mem instrs), lane-quad kg split
//   (shfl reduce, 1 barrier/step, double-buffered h), xrow prefetch.
//   Classifier: 128x128 tiles, ct-major for W L2 residency.

#define B 32
#define T 160
#define D 512
#define H 256
#define C 6625
#define H3 768
#define NT16 416                  // 52*8 16-col W tiles (padded past 6625)
#define RKQ_U4_PER_DIR 24576      // 32 o * 768 c  (uint4 each)

typedef __attribute__((ext_vector_type(8))) short short8v;
typedef __attribute__((ext_vector_type(4))) float float4v;

__device__ inline unsigned short f2bf(float v) {
    __hip_bfloat16 b = __float2bfloat16(v);
    return *reinterpret_cast<unsigned short*>(&b);
}
__device__ inline float bflo(unsigned int u) { return __uint_as_float(u << 16); }
__device__ inline float bfhi(unsigned int u) { return __uint_as_float(u & 0xffff0000u); }

// ---------------------------------------------------------------- pack rk -> uint4 rows
// rkQ[dir][o][c] = uint4{ bf16x2(rk[8o+0][c],rk[8o+1][c]), bf16x2(rk[8o+2],rk[8o+3]),
//                         bf16x2(rk[8o+4],rk[8o+5]),       bf16x2(rk[8o+6],rk[8o+7]) }
// o = 0..31 (k-octet), c = 0..767 raw column (z|r|h gate bands).
__global__ __launch_bounds__(256) void pack_rk4_kernel(
    const float* __restrict__ rkf, const float* __restrict__ rkb,
    unsigned int* __restrict__ rkQ)
{
    const int idx = blockIdx.x * 256 + threadIdx.x;   // 0..98303 (dwords per dir)
    const int dir = blockIdx.y;
    const float* rk = dir ? rkb : rkf;
    const int e    = idx & 3;
    const int rest = idx >> 2;
    const int c    = rest % H3;
    const int o    = rest / H3;
    const int k0   = 8 * o + 2 * e;
    unsigned int lo = f2bf(rk[k0 * H3 + c]);
    unsigned int hi = f2bf(rk[(k0 + 1) * H3 + c]);
    rkQ[dir * (RKQ_U4_PER_DIR * 4) + idx] = (hi << 16) | lo;
}

// ---------------------------------------------------------------- pack W
// Wp[nt][kc][col][i] = bf16( W[kc*8+i][nt*16+col] ), zero-padded cols.
__global__ __launch_bounds__(256) void pack_W_kernel(
    const float* __restrict__ W, unsigned short* __restrict__ Wp)
{
    const int idx = blockIdx.x * 256 + threadIdx.x;   // < 416*8192
    const int i   = idx & 7;
    const int col = (idx >> 3) & 15;
    const int kc  = (idx >> 7) & 63;
    const int nt  = idx >> 13;
    const int k = kc * 8 + i;
    const int c = nt * 16 + col;
    const float v = (c < C) ? W[k * C + c] : 0.f;
    Wp[idx] = f2bf(v);
}

// ---------------------------------------------------------------- K1: proj
__global__ __launch_bounds__(256) void proj_kernel(
    const float* __restrict__ x,       // [B][T][D]
    const float* __restrict__ kf,      // [D][H3]
    const float* __restrict__ kb,
    const float* __restrict__ bias_f,  // [2][H3]
    const float* __restrict__ bias_b,
    float* __restrict__ xp)            // [2][T][B][H3]
{
    const int ct  = blockIdx.x;
    const int s   = blockIdx.y;
    const int dir = blockIdx.z;
    const int tid = threadIdx.x;
    const int t   = dir ? (T - 1 - s) : s;
    const float* kern = dir ? kb : kf;
    const float* bias = dir ? bias_b : bias_f;

    __shared__ float xs[32 * 512];
    for (int it = 0; it < 16; ++it) {
        int v   = it * 256 + tid;
        int row = v >> 7;
        int k4  = v & 127;
        *(float4*)&xs[(row << 9) + (k4 << 2)] =
            *(const float4*)&x[((row * T + t) << 9) + (k4 << 2)];
    }
    __syncthreads();

    const int col = ct * 256 + tid;
    float acc[32];
#pragma unroll
    for (int r = 0; r < 32; ++r) acc[r] = 0.f;

    for (int k = 0; k < 512; k += 4) {
        float w0 = kern[(k + 0) * H3 + col];
        float w1 = kern[(k + 1) * H3 + col];
        float w2 = kern[(k + 2) * H3 + col];
        float w3 = kern[(k + 3) * H3 + col];
#pragma unroll
        for (int r = 0; r < 32; ++r) {
            float4 xv = *(const float4*)&xs[(r << 9) + k];
            acc[r] += xv.x * w0 + xv.y * w1 + xv.z * w2 + xv.w * w3;
        }
    }

    const float bb = bias[col];
    for (int r = 0; r < 32; ++r)
        xp[((dir * T + s) * B + r) * H3 + col] = acc[r] + bb;
}

// ---------------------------------------------------------------- K2: scan v4
// grid 64 = (dir<<5)|b, block 1024. Thread (j = tid>>2, kg = tid&3):
// partial dots over k in [kg*64, +64) for gate cols {j, j+256, j+512},
// weights as uint4 (8 k per load per gate). Quad shfl_xor reduce; kg==0
// lanes do gate math. h double-buffered in LDS -> ONE barrier per step.
__global__ __launch_bounds__(1024) void gru_scan_v4(
    const float* __restrict__ xp,       // [2][T][B][H3] fp32
    const unsigned int* __restrict__ rkQd,
    const float* __restrict__ bias_f,
    const float* __restrict__ bias_b,
    __hip_bfloat16* __restrict__ hcatb) // [T][B][2H] bf16
{
    const int bid = blockIdx.x;
    const int dir = bid >> 5;
    const int b   = bid & 31;
    const int tid = threadIdx.x;
    const int j   = tid >> 2;          // 0..255 output column
    const int kg  = tid & 3;           // 0..3 k-quarter
    const uint4* rq = (const uint4*)(rkQd + dir * (RKQ_U4_PER_DIR * 4));
    const float* bias = dir ? bias_b : bias_f;

    float rbz = 0.f, rbr = 0.f, rbh = 0.f;
    if (kg == 0) {
        rbz = bias[H3 + j];
        rbr = bias[H3 + 256 + j];
        rbh = bias[H3 + 512 + j];
    }

    __shared__ float hA[256], hB[256];
    if (tid < 256) hA[tid] = 0.f;
    __syncthreads();

    for (int s = 0; s < T; ++s) {
        const float* cur = (s & 1) ? hB : hA;
        float*       nxt = (s & 1) ? hA : hB;

        // prefetch this step's x-projection row (overlaps the FMA loop)
        float xz = 0.f, xr = 0.f, xh = 0.f;
        if (kg == 0) {
            const float* xrow = xp + ((dir * T + s) * B + b) * H3;
            xz = xrow[j];
            xr = xrow[256 + j];
            xh = xrow[512 + j];
        }

        float az = 0.f, ar = 0.f, ah = 0.f;
#pragma unroll 2
        for (int oi = 0; oi < 8; ++oi) {
            const int o = (kg << 3) + ((oi + kg) & 7);   // bank-staggered order
            const uint4 dz = rq[o * H3 + j];
            const uint4 dr = rq[o * H3 + 256 + j];
            const uint4 dh = rq[o * H3 + 512 + j];
            const float4 ha = *(const float4*)&cur[o * 8];
            const float4 hb = *(const float4*)&cur[o * 8 + 4];
            az += ha.x * bflo(dz.x) + ha.y * bfhi(dz.x)
                + ha.z * bflo(dz.y) + ha.w * bfhi(dz.y)
                + hb.x * bflo(dz.z) + hb.y * bfhi(dz.z)
                + hb.z * bflo(dz.w) + hb.w * bfhi(dz.w);
            ar += ha.x * bflo(dr.x) + ha.y * bfhi(dr.x)
                + ha.z * bflo(dr.y) + ha.w * bfhi(dr.y)
                + hb.x * bflo(dr.z) + hb.y * bfhi(dr.z)
                + hb.z * bflo(dr.w) + hb.w * bfhi(dr.w);
            ah += ha.x * bflo(dh.x) + ha.y * bfhi(dh.x)
                + ha.z * bflo(dh.y) + ha.w * bfhi(dh.y)
                + hb.x * bflo(dh.z) + hb.y * bfhi(dh.z)
                + hb.z * bflo(dh.w) + hb.w * bfhi(dh.w);
        }

        // reduce across kg (lanes j*4+kg: xor 1,2 stay within the quad)
        az += __shfl_xor(az, 1, 64);  az += __shfl_xor(az, 2, 64);
        ar += __shfl_xor(ar, 1, 64);  ar += __shfl_xor(ar, 2, 64);
        ah += __shfl_xor(ah, 1, 64);  ah += __shfl_xor(ah, 2, 64);

        if (kg == 0) {
            const float z  = 1.f / (1.f + __expf(-(xz + az + rbz)));
            const float r  = 1.f / (1.f + __expf(-(xr + ar + rbr)));
            const float pre = xh + r * (ah + rbh);
            const float e2  = __expf(2.f * pre);
            const float hh  = 1.f - 2.f / (e2 + 1.f);    // tanh, inf-safe
            const float hn  = z * cur[j] + (1.f - z) * hh;
            nxt[j] = hn;
            const int ta = dir ? (T - 1 - s) : s;
            hcatb[(ta * B + b) * 512 + dir * 256 + j] = __float2bfloat16(hn);
        }
        __syncthreads();        // next-step h complete; also guards cur reuse
    }
}

// ---------------------------------------------------------------- K3: MFMA classifier
// grid 2080 = 52 ct x 40 rt, ct-major (consecutive blocks share the 128 KB
// W slice -> L2-resident). Block 256 = 4 waves (2x2); wave tile 64x64.
__global__ __launch_bounds__(256) void cls_mfma_kernel(
    const __hip_bfloat16* __restrict__ hcatb,
    const unsigned short* __restrict__ Wp,
    const float* __restrict__ bias,
    float* __restrict__ out)
{
    const int bid = blockIdx.x;
    const int ct  = bid / 40;          // 0..51
    const int rt  = bid % 40;          // 0..39
    const int lane = threadIdx.x & 63;
    const int wid  = threadIdx.x >> 6;
    const int wm = wid >> 1, wn = wid & 1;
    const int rowBase = rt * 128 + wm * 64;
    const int lrow = lane & 15;
    const int lk8  = lane >> 4;        // 0..3

    float4v acc[4][4];
#pragma unroll
    for (int i = 0; i < 4; ++i)
#pragma unroll
        for (int k = 0; k < 4; ++k) acc[i][k] = (float4v){0.f, 0.f, 0.f, 0.f};

    const short* A  = (const short*)hcatb;
    const short* Bp = (const short*)Wp;
    const int ntBase = ct * 8 + wn * 4;

    for (int k0 = 0; k0 < 512; k0 += 32) {
        short8v aF[4], bF[4];
#pragma unroll
        for (int mt = 0; mt < 4; ++mt)
            aF[mt] = *(const short8v*)&A[(rowBase + mt * 16 + lrow) * 512 + k0 + lk8 * 8];
#pragma unroll
        for (int ntw = 0; ntw < 4; ++ntw)
            bF[ntw] = *(const short8v*)&Bp[((ntBase + ntw) * 64 + (k0 >> 3) + lk8) * 128 + lrow * 8];
#pragma unroll
        for (int mt = 0; mt < 4; ++mt)
#pragma unroll
            for (int ntw = 0; ntw < 4; ++ntw)
                acc[mt][ntw] = __builtin_amdgcn_mfma_f32_16x16x32_bf16(
                    aF[mt], bF[ntw], acc[mt][ntw], 0, 0, 0);
    }

    const int orow = (lane >> 4) * 4;   // C/D: col=lane&15, row=(lane>>4)*4+reg
#pragma unroll
    for (int ntw = 0; ntw < 4; ++ntw) {
        const int c = (ntBase + ntw) * 16 + lrow;
        if (c >= C) continue;
        const float bc = bias[c];
#pragma unroll
        for (int mt = 0; mt < 4; ++mt)
#pragma unroll
            for (int v = 0; v < 4; ++v)
                out[(size_t)(rowBase + mt * 16 + orow + v) * C + c] = acc[mt][ntw][v] + bc;
    }
}

// ============================ fallback fp32 path (small ws) ============================
__global__ __launch_bounds__(1024) void gru_scan_f32(
    const float* __restrict__ xp,
    const float* __restrict__ rk_f, const float* __restrict__ rk_b,
    const float* __restrict__ bias_f, const float* __restrict__ bias_b,
    float* __restrict__ hcat)
{
    const int bid = blockIdx.x;
    const int dir = bid >> 5;
    const int b   = bid & 31;
    const int tid = threadIdx.x;
    const int kg  = tid >> 8;
    const int j   = tid & 255;
    const int k0  = kg << 6;
    const float* rk   = dir ? rk_b : rk_f;
    const float* bias = dir ? bias_b : bias_f;
    const float rbz = bias[H3 + j];
    const float rbr = bias[H3 + 256 + j];
    const float rbh = bias[H3 + 512 + j];

    __shared__ float h[256];
    __shared__ float part[3][4][256];
    if (tid < 256) h[tid] = 0.f;
    __syncthreads();

    for (int s = 0; s < T; ++s) {
        const float* xrow = xp + ((dir * T + s) * B + b) * H3;
        float az = 0.f, ar = 0.f, ah = 0.f;
#pragma unroll 4
        for (int k = k0; k < k0 + 64; k += 4) {
            float4 h4 = *(const float4*)&h[k];
            const float* rkp = rk + k * H3 + j;
            az += h4.x * rkp[0];       ar += h4.x * rkp[256];       ah += h4.x * rkp[512];
            az += h4.y * rkp[H3];      ar += h4.y * rkp[H3+256];    ah += h4.y * rkp[H3+512];
            az += h4.z * rkp[2*H3];    ar += h4.z * rkp[2*H3+256];  ah += h4.z * rkp[2*H3+512];
            az += h4.w * rkp[3*H3];    ar += h4.w * rkp[3*H3+256];  ah += h4.w * rkp[3*H3+512];
        }
        part[0][kg][j] = az; part[1][kg][j] = ar; part[2][kg][j] = ah;
        __syncthreads();
        if (tid < 256) {
            const float sz = part[0][0][tid]+part[0][1][tid]+part[0][2][tid]+part[0][3][tid];
            const float sr = part[1][0][tid]+part[1][1][tid]+part[1][2][tid]+part[1][3][tid];
            const float sh = part[2][0][tid]+part[2][1][tid]+part[2][2][tid]+part[2][3][tid];
            const float xz = xrow[tid], xr = xrow[256+tid], xh = xrow[512+tid];
            const float z  = 1.f / (1.f + __expf(-(xz + sz + rbz)));
            const float r  = 1.f / (1.f + __expf(-(xr + sr + rbr)));
            const float pre = xh + r * (sh + rbh);
            const float e2  = __expf(2.f * pre);
            const float hh  = 1.f - 2.f / (e2 + 1.f);
            const float hn  = z * h[tid] + (1.f - z) * hh;
            h[tid] = hn;
            const int ta = dir ? (T - 1 - s) : s;
            hcat[(ta * B + b) * (2 * H) + dir * H + tid] = hn;
        }
        __syncthreads();
    }
}

__global__ __launch_bounds__(256) void cls_f32_kernel(
    const float* __restrict__ hcat, const float* __restrict__ W,
    const float* __restrict__ bias, float* __restrict__ out)
{
    const int bid = blockIdx.x;
    const int ct  = bid / 160;
    const int rt  = bid % 160;
    const int tid = threadIdx.x;
    const int r0  = rt * 32;

    __shared__ float hs[32 * 512];
    for (int it = 0; it < 16; ++it) {
        int v = it * 256 + tid, row = v >> 7, k4 = v & 127;
        *(float4*)&hs[(row << 9) + (k4 << 2)] =
            *(const float4*)&hcat[((r0 + row) << 9) + (k4 << 2)];
    }
    __syncthreads();

    const int c0 = ct * 512 + tid;
    const int c1 = c0 + 256;
    const bool v1 = (c1 < C);
    float acc0[32], acc1[32];
#pragma unroll
    for (int r = 0; r < 32; ++r) { acc0[r] = 0.f; acc1[r] = 0.f; }
    for (int k = 0; k < 512; k += 4) {
        const float* wp = W + k * C;
        float w00 = wp[c0], w01 = wp[C+c0], w02 = wp[2*C+c0], w03 = wp[3*C+c0];
        float w10 = v1 ? wp[c1] : 0.f, w11 = v1 ? wp[C+c1] : 0.f;
        float w12 = v1 ? wp[2*C+c1] : 0.f, w13 = v1 ? wp[3*C+c1] : 0.f;
#pragma unroll
        for (int r = 0; r < 32; ++r) {
            float4 hv = *(const float4*)&hs[(r << 9) + k];
            acc0[r] += hv.x*w00 + hv.y*w01 + hv.z*w02 + hv.w*w03;
            acc1[r] += hv.x*w10 + hv.y*w11 + hv.z*w12 + hv.w*w13;
        }
    }
    const float b0 = bias[c0];
    const float b1 = v1 ? bias[c1] : 0.f;
    for (int r = 0; r < 32; ++r) {
        out[(size_t)(r0+r)*C + c0] = acc0[r] + b0;
        if (v1) out[(size_t)(r0+r)*C + c1] = acc1[r] + b1;
    }
}

// ---------------------------------------------------------------- launch
extern "C" void kernel_launch(void* const* d_in, const int* in_sizes, int n_in,
                              void* d_out, int out_size, void* d_ws, size_t ws_size,
                              hipStream_t stream) {
    const float* x     = (const float*)d_in[0];
    const float* kf    = (const float*)d_in[1];
    const float* rkf   = (const float*)d_in[2];
    const float* biasf = (const float*)d_in[3];
    const float* kb    = (const float*)d_in[4];
    const float* rkb   = (const float*)d_in[5];
    const float* biasb = (const float*)d_in[6];
    const float* W     = (const float*)d_in[7];
    const float* bvec  = (const float*)d_in[8];
    float* out = (float*)d_out;

    const size_t rkQ_bytes   = (size_t)2 * RKQ_U4_PER_DIR * 16;    //   786,432
    const size_t Wp_bytes    = (size_t)NT16 * 8192 * 2;            // 6,815,744
    const size_t hcatb_bytes = (size_t)T * B * 2 * H * 2;          // 5,242,880
    const size_t planA_bytes = rkQ_bytes + Wp_bytes + hcatb_bytes; // 12,845,056

    float* xp = out;   // xp [2][T][B][H3] lives in d_out; dead before cls writes

    if (ws_size >= planA_bytes) {
        char* wsb = (char*)d_ws;
        unsigned int*   rkQ   = (unsigned int*)wsb;
        unsigned short* Wp    = (unsigned short*)(wsb + rkQ_bytes);
        __hip_bfloat16* hcatb = (__hip_bfloat16*)(wsb + rkQ_bytes + Wp_bytes);

        pack_rk4_kernel<<<dim3(384, 2), 256, 0, stream>>>(rkf, rkb, rkQ);
        pack_W_kernel<<<13312, 256, 0, stream>>>(W, Wp);

        dim3 g1(3, T, 2);
        proj_kernel<<<g1, 256, 0, stream>>>(x, kf, kb, biasf, biasb, xp);

        gru_scan_v4<<<64, 1024, 0, stream>>>(xp, rkQ, biasf, biasb, hcatb);

        cls_mfma_kernel<<<2080, 256, 0, stream>>>(hcatb, Wp, bvec, out);
    } else {
        // fp32 fallback (round-2 path)
        float* hcat = (float*)d_ws;     // 10.5 MB
        dim3 g1(3, T, 2);
        proj_kernel<<<g1, 256, 0, stream>>>(x, kf, kb, biasf, biasb, xp);
        gru_scan_f32<<<64, 1024, 0, stream>>>(xp, rkf, rkb, biasf, biasb, hcat);
        cls_f32_kernel<<<13 * 160, 256, 0, stream>>>(hcat, W, bvec, out);
    }
}

// Round 6
// 527.963 us; speedup vs baseline: 3.9904x; 3.9904x over previous
//
#include <hip/hip_runtime.h>
#include <hip/hip_bf16.h>

// Bidirectional GRU (Keras reset_after=True) + dense classifier.
// B=32, T=160, D=512, H=256, C=6625.
// Round 6: weights-in-VGPR scan, single WG per (dir,b) -- no cross-WG sync,
//   no per-step weight re-streaming. 768 thr = (gate g, col j); thread holds
//   its gate-column (256 k = 128 bf16x2 dwords = 128 VGPRs). h broadcast from
//   LDS; v_dot2_f32_bf16 if available, unpack+FMA fallback.
//   proj / cls_mfma unchanged from R5.

#define B 32
#define T 160
#define D 512
#define H 256
#define C 6625
#define H3 768
#define NT16 416                  // 52*8 16-col W tiles (padded past 6625)

typedef __attribute__((ext_vector_type(8))) short short8v;
typedef __attribute__((ext_vector_type(4))) float float4v;

__device__ inline unsigned short f2bf(float v) {
    __hip_bfloat16 b = __float2bfloat16(v);
    return *reinterpret_cast<unsigned short*>(&b);
}
__device__ inline float bflo(unsigned int u) { return __uint_as_float(u << 16); }
__device__ inline float bfhi(unsigned int u) { return __uint_as_float(u & 0xffff0000u); }

#if __has_builtin(__builtin_amdgcn_fdot2_f32_bf16)
#define HAVE_DOT2 1
typedef __attribute__((ext_vector_type(2))) __bf16 bf16x2v;
__device__ inline float dot2bf(unsigned int w, unsigned int h, float acc) {
    return __builtin_amdgcn_fdot2_f32_bf16(
        __builtin_bit_cast(bf16x2v, w), __builtin_bit_cast(bf16x2v, h), acc, false);
}
#else
#define HAVE_DOT2 0
#endif

// ---------------------------------------------------------------- pack rkT
// rkT[dir][g][p][j] = bf16x2( rk[2p][g*256+j], rk[2p+1][g*256+j] )
// -> thread (g,j)'s weight dwords are at stride 256, lane-j coalesced.
__global__ __launch_bounds__(256) void pack_rkT_kernel(
    const float* __restrict__ rkf, const float* __restrict__ rkb,
    unsigned int* __restrict__ rkT)
{
    const int idx = blockIdx.x * 256 + threadIdx.x;   // 0..196607
    const int j   = idx & 255;
    const int p   = (idx >> 8) & 127;
    const int g   = (idx >> 15) % 3;
    const int dir = idx / (3 << 15);
    const float* rk = dir ? rkb : rkf;
    const int col = g * 256 + j;
    unsigned int lo = f2bf(rk[(2 * p) * H3 + col]);
    unsigned int hi = f2bf(rk[(2 * p + 1) * H3 + col]);
    rkT[idx] = (hi << 16) | lo;
}

// ---------------------------------------------------------------- pack W
// Wp[nt][kc][col][i] = bf16( W[kc*8+i][nt*16+col] ), zero-padded cols.
__global__ __launch_bounds__(256) void pack_W_kernel(
    const float* __restrict__ W, unsigned short* __restrict__ Wp)
{
    const int idx = blockIdx.x * 256 + threadIdx.x;   // < 416*8192
    const int i   = idx & 7;
    const int col = (idx >> 3) & 15;
    const int kc  = (idx >> 7) & 63;
    const int nt  = idx >> 13;
    const int k = kc * 8 + i;
    const int c = nt * 16 + col;
    const float v = (c < C) ? W[k * C + c] : 0.f;
    Wp[idx] = f2bf(v);
}

// ---------------------------------------------------------------- K1: proj
__global__ __launch_bounds__(256) void proj_kernel(
    const float* __restrict__ x,       // [B][T][D]
    const float* __restrict__ kf,      // [D][H3]
    const float* __restrict__ kb,
    const float* __restrict__ bias_f,  // [2][H3]
    const float* __restrict__ bias_b,
    float* __restrict__ xp)            // [2][T][B][H3]
{
    const int ct  = blockIdx.x;
    const int s   = blockIdx.y;
    const int dir = blockIdx.z;
    const int tid = threadIdx.x;
    const int t   = dir ? (T - 1 - s) : s;
    const float* kern = dir ? kb : kf;
    const float* bias = dir ? bias_b : bias_f;

    __shared__ float xs[32 * 512];
    for (int it = 0; it < 16; ++it) {
        int v   = it * 256 + tid;
        int row = v >> 7;
        int k4  = v & 127;
        *(float4*)&xs[(row << 9) + (k4 << 2)] =
            *(const float4*)&x[((row * T + t) << 9) + (k4 << 2)];
    }
    __syncthreads();

    const int col = ct * 256 + tid;
    float acc[32];
#pragma unroll
    for (int r = 0; r < 32; ++r) acc[r] = 0.f;

    for (int k = 0; k < 512; k += 4) {
        float w0 = kern[(k + 0) * H3 + col];
        float w1 = kern[(k + 1) * H3 + col];
        float w2 = kern[(k + 2) * H3 + col];
        float w3 = kern[(k + 3) * H3 + col];
#pragma unroll
        for (int r = 0; r < 32; ++r) {
            float4 xv = *(const float4*)&xs[(r << 9) + k];
            acc[r] += xv.x * w0 + xv.y * w1 + xv.z * w2 + xv.w * w3;
        }
    }

    const float bb = bias[col];
    for (int r = 0; r < 32; ++r)
        xp[((dir * T + s) * B + r) * H3 + col] = acc[r] + bb;
}

// ---------------------------------------------------------------- K2: scan v5
// grid 64 = (dir<<5)|b, block 768. Thread (g = tid>>8 in 0..2, j = tid&255)
// owns gate-g column j: 256 k of weights = 128 bf16x2 dwords IN VGPRS.
// Per step: full 256-k dot via dot2 (h bf16 pairs, LDS broadcast read),
// g>0 write dot to LDS; threads 0..255 do gate math + h update. 2 barriers.
__global__ __launch_bounds__(768, 3) void gru_scan_v5(
    const float* __restrict__ xp,        // [2][T][B][H3] fp32
    const unsigned int* __restrict__ rkT, // [2][3][128][256]
    const float* __restrict__ bias_f,
    const float* __restrict__ bias_b,
    __hip_bfloat16* __restrict__ hcatb)  // [T][B][2H] bf16
{
    const int bid = blockIdx.x;
    const int dir = bid >> 5;
    const int b   = bid & 31;
    const int tid = threadIdx.x;
    const int g   = tid >> 8;          // 0..2 (wave-uniform)
    const int j   = tid & 255;
    const float* bias = dir ? bias_b : bias_f;

    // ---- one-time: weights into VGPRs (coalesced: lane j contiguous) ----
    const unsigned int* wsrc = rkT + ((dir * 3 + g) << 15) + j;
    unsigned int w[128];
#pragma unroll
    for (int p = 0; p < 128; ++p) w[p] = wsrc[p << 8];

    float rbz = 0.f, rbr = 0.f, rbh = 0.f;
    if (tid < 256) {
        rbz = bias[H3 + j];
        rbr = bias[H3 + 256 + j];
        rbh = bias[H3 + 512 + j];
    }

    __shared__ float hfp[256];          // fp32 h (for z*h_old and fallback)
    __shared__ unsigned int hbf[128];   // bf16x2 h pairs (dot2 path)
    __shared__ float sums[2][256];      // r,h gate dots from g=1,2
    if (tid < 256) hfp[tid] = 0.f;
    if (tid < 128) hbf[tid] = 0u;
    __syncthreads();

    for (int s = 0; s < T; ++s) {
        float xz = 0.f, xr = 0.f, xh = 0.f;
        if (tid < 256) {                // prefetch, overlaps dot loop
            const float* xrow = xp + ((dir * T + s) * B + b) * H3;
            xz = xrow[j];
            xr = xrow[256 + j];
            xh = xrow[512 + j];
        }

        float a0 = 0.f, a1 = 0.f, a2 = 0.f, a3 = 0.f;
#if HAVE_DOT2
        {
            const uint4* h4 = (const uint4*)hbf;
#pragma unroll
            for (int q = 0; q < 32; ++q) {
                uint4 hv = h4[q];       // all 64 lanes same addr: broadcast
                a0 = dot2bf(w[4 * q + 0], hv.x, a0);
                a1 = dot2bf(w[4 * q + 1], hv.y, a1);
                a2 = dot2bf(w[4 * q + 2], hv.z, a2);
                a3 = dot2bf(w[4 * q + 3], hv.w, a3);
                if ((q & 7) == 7) __builtin_amdgcn_sched_barrier(0); // cap h in flight
            }
        }
#else
#pragma unroll
        for (int q = 0; q < 32; ++q) {
            float4 h01 = *(const float4*)&hfp[8 * q];
            float4 h23 = *(const float4*)&hfp[8 * q + 4];
            a0 += h01.x * bflo(w[4 * q + 0]) + h01.y * bfhi(w[4 * q + 0]);
            a1 += h01.z * bflo(w[4 * q + 1]) + h01.w * bfhi(w[4 * q + 1]);
            a2 += h23.x * bflo(w[4 * q + 2]) + h23.y * bfhi(w[4 * q + 2]);
            a3 += h23.z * bflo(w[4 * q + 3]) + h23.w * bfhi(w[4 * q + 3]);
            if ((q & 7) == 7) __builtin_amdgcn_sched_barrier(0);
        }
#endif
        const float dot = (a0 + a1) + (a2 + a3);
        if (g > 0) sums[g - 1][j] = dot;
        __syncthreads();                // r,h dots visible

        if (tid < 256) {                // g==0: own dot is the z gate
            const float sz = dot;
            const float sr = sums[0][j];
            const float sh = sums[1][j];
            const float z  = 1.f / (1.f + __expf(-(xz + sz + rbz)));
            const float r  = 1.f / (1.f + __expf(-(xr + sr + rbr)));
            const float pre = xh + r * (sh + rbh);
            const float e2  = __expf(2.f * pre);
            const float hh  = 1.f - 2.f / (e2 + 1.f);   // tanh, inf-safe
            const float hn  = z * hfp[j] + (1.f - z) * hh;
            hfp[j] = hn;
#if HAVE_DOT2
            ((unsigned short*)hbf)[j] = f2bf(hn);
#endif
            const int ta = dir ? (T - 1 - s) : s;
            hcatb[(ta * B + b) * 512 + dir * 256 + j] = __float2bfloat16(hn);
        }
        __syncthreads();                // h_{s+1} ready for next dot loop
    }
}

// ---------------------------------------------------------------- K3: MFMA classifier
// grid 2080 = 52 ct x 40 rt, ct-major (consecutive blocks share the 128 KB
// W slice -> L2-resident). Block 256 = 4 waves (2x2); wave tile 64x64.
__global__ __launch_bounds__(256) void cls_mfma_kernel(
    const __hip_bfloat16* __restrict__ hcatb,
    const unsigned short* __restrict__ Wp,
    const float* __restrict__ bias,
    float* __restrict__ out)
{
    const int bid = blockIdx.x;
    const int ct  = bid / 40;          // 0..51
    const int rt  = bid % 40;          // 0..39
    const int lane = threadIdx.x & 63;
    const int wid  = threadIdx.x >> 6;
    const int wm = wid >> 1, wn = wid & 1;
    const int rowBase = rt * 128 + wm * 64;
    const int lrow = lane & 15;
    const int lk8  = lane >> 4;        // 0..3

    float4v acc[4][4];
#pragma unroll
    for (int i = 0; i < 4; ++i)
#pragma unroll
        for (int k = 0; k < 4; ++k) acc[i][k] = (float4v){0.f, 0.f, 0.f, 0.f};

    const short* A  = (const short*)hcatb;
    const short* Bp = (const short*)Wp;
    const int ntBase = ct * 8 + wn * 4;

    for (int k0 = 0; k0 < 512; k0 += 32) {
        short8v aF[4], bF[4];
#pragma unroll
        for (int mt = 0; mt < 4; ++mt)
            aF[mt] = *(const short8v*)&A[(rowBase + mt * 16 + lrow) * 512 + k0 + lk8 * 8];
#pragma unroll
        for (int ntw = 0; ntw < 4; ++ntw)
            bF[ntw] = *(const short8v*)&Bp[((ntBase + ntw) * 64 + (k0 >> 3) + lk8) * 128 + lrow * 8];
#pragma unroll
        for (int mt = 0; mt < 4; ++mt)
#pragma unroll
            for (int ntw = 0; ntw < 4; ++ntw)
                acc[mt][ntw] = __builtin_amdgcn_mfma_f32_16x16x32_bf16(
                    aF[mt], bF[ntw], acc[mt][ntw], 0, 0, 0);
    }

    const int orow = (lane >> 4) * 4;   // C/D: col=lane&15, row=(lane>>4)*4+reg
#pragma unroll
    for (int ntw = 0; ntw < 4; ++ntw) {
        const int c = (ntBase + ntw) * 16 + lrow;
        if (c >= C) continue;
        const float bc = bias[c];
#pragma unroll
        for (int mt = 0; mt < 4; ++mt)
#pragma unroll
            for (int v = 0; v < 4; ++v)
                out[(size_t)(rowBase + mt * 16 + orow + v) * C + c] = acc[mt][ntw][v] + bc;
    }
}

// ============================ fallback fp32 path (small ws) ============================
__global__ __launch_bounds__(1024) void gru_scan_f32(
    const float* __restrict__ xp,
    const float* __restrict__ rk_f, const float* __restrict__ rk_b,
    const float* __restrict__ bias_f, const float* __restrict__ bias_b,
    float* __restrict__ hcat)
{
    const int bid = blockIdx.x;
    const int dir = bid >> 5;
    const int b   = bid & 31;
    const int tid = threadIdx.x;
    const int kg  = tid >> 8;
    const int j   = tid & 255;
    const int k0  = kg << 6;
    const float* rk   = dir ? rk_b : rk_f;
    const float* bias = dir ? bias_b : bias_f;
    const float rbz = bias[H3 + j];
    const float rbr = bias[H3 + 256 + j];
    const float rbh = bias[H3 + 512 + j];

    __shared__ float h[256];
    __shared__ float part[3][4][256];
    if (tid < 256) h[tid] = 0.f;
    __syncthreads();

    for (int s = 0; s < T; ++s) {
        const float* xrow = xp + ((dir * T + s) * B + b) * H3;
        float az = 0.f, ar = 0.f, ah = 0.f;
#pragma unroll 4
        for (int k = k0; k < k0 + 64; k += 4) {
            float4 h4 = *(const float4*)&h[k];
            const float* rkp = rk + k * H3 + j;
            az += h4.x * rkp[0];       ar += h4.x * rkp[256];       ah += h4.x * rkp[512];
            az += h4.y * rkp[H3];      ar += h4.y * rkp[H3+256];    ah += h4.y * rkp[H3+512];
            az += h4.z * rkp[2*H3];    ar += h4.z * rkp[2*H3+256];  ah += h4.z * rkp[2*H3+512];
            az += h4.w * rkp[3*H3];    ar += h4.w * rkp[3*H3+256];  ah += h4.w * rkp[3*H3+512];
        }
        part[0][kg][j] = az; part[1][kg][j] = ar; part[2][kg][j] = ah;
        __syncthreads();
        if (tid < 256) {
            const float sz = part[0][0][tid]+part[0][1][tid]+part[0][2][tid]+part[0][3][tid];
            const float sr = part[1][0][tid]+part[1][1][tid]+part[1][2][tid]+part[1][3][tid];
            const float sh = part[2][0][tid]+part[2][1][tid]+part[2][2][tid]+part[2][3][tid];
            const float xz = xrow[tid], xr = xrow[256+tid], xh = xrow[512+tid];
            const float z  = 1.f / (1.f + __expf(-(xz + sz + rbz)));
            const float r  = 1.f / (1.f + __expf(-(xr + sr + rbr)));
            const float pre = xh + r * (sh + rbh);
            const float e2  = __expf(2.f * pre);
            const float hh  = 1.f - 2.f / (e2 + 1.f);
            const float hn  = z * h[tid] + (1.f - z) * hh;
            h[tid] = hn;
            const int ta = dir ? (T - 1 - s) : s;
            hcat[(ta * B + b) * (2 * H) + dir * H + tid] = hn;
        }
        __syncthreads();
    }
}

__global__ __launch_bounds__(256) void cls_f32_kernel(
    const float* __restrict__ hcat, const float* __restrict__ W,
    const float* __restrict__ bias, float* __restrict__ out)
{
    const int bid = blockIdx.x;
    const int ct  = bid / 160;
    const int rt  = bid % 160;
    const int tid = threadIdx.x;
    const int r0  = rt * 32;

    __shared__ float hs[32 * 512];
    for (int it = 0; it < 16; ++it) {
        int v = it * 256 + tid, row = v >> 7, k4 = v & 127;
        *(float4*)&hs[(row << 9) + (k4 << 2)] =
            *(const float4*)&hcat[((r0 + row) << 9) + (k4 << 2)];
    }
    __syncthreads();

    const int c0 = ct * 512 + tid;
    const int c1 = c0 + 256;
    const bool v1 = (c1 < C);
    float acc0[32], acc1[32];
#pragma unroll
    for (int r = 0; r < 32; ++r) { acc0[r] = 0.f; acc1[r] = 0.f; }
    for (int k = 0; k < 512; k += 4) {
        const float* wp = W + k * C;
        float w00 = wp[c0], w01 = wp[C+c0], w02 = wp[2*C+c0], w03 = wp[3*C+c0];
        float w10 = v1 ? wp[c1] : 0.f, w11 = v1 ? wp[C+c1] : 0.f;
        float w12 = v1 ? wp[2*C+c1] : 0.f, w13 = v1 ? wp[3*C+c1] : 0.f;
#pragma unroll
        for (int r = 0; r < 32; ++r) {
            float4 hv = *(const float4*)&hs[(r << 9) + k];
            acc0[r] += hv.x*w00 + hv.y*w01 + hv.z*w02 + hv.w*w03;
            acc1[r] += hv.x*w10 + hv.y*w11 + hv.z*w12 + hv.w*w13;
        }
    }
    const float b0 = bias[c0];
    const float b1 = v1 ? bias[c1] : 0.f;
    for (int r = 0; r < 32; ++r) {
        out[(size_t)(r0+r)*C + c0] = acc0[r] + b0;
        if (v1) out[(size_t)(r0+r)*C + c1] = acc1[r] + b1;
    }
}

// ---------------------------------------------------------------- launch
extern "C" void kernel_launch(void* const* d_in, const int* in_sizes, int n_in,
                              void* d_out, int out_size, void* d_ws, size_t ws_size,
                              hipStream_t stream) {
    const float* x     = (const float*)d_in[0];
    const float* kf    = (const float*)d_in[1];
    const float* rkf   = (const float*)d_in[2];
    const float* biasf = (const float*)d_in[3];
    const float* kb    = (const float*)d_in[4];
    const float* rkb   = (const float*)d_in[5];
    const float* biasb = (const float*)d_in[6];
    const float* W     = (const float*)d_in[7];
    const float* bvec  = (const float*)d_in[8];
    float* out = (float*)d_out;

    const size_t rkT_bytes   = (size_t)2 * 3 * 128 * 256 * 4;     //   786,432
    const size_t Wp_bytes    = (size_t)NT16 * 8192 * 2;           // 6,815,744
    const size_t hcatb_bytes = (size_t)T * B * 2 * H * 2;         // 5,242,880
    const size_t planA_bytes = rkT_bytes + Wp_bytes + hcatb_bytes;

    float* xp = out;   // xp [2][T][B][H3] lives in d_out; dead before cls writes

    if (ws_size >= planA_bytes) {
        char* wsb = (char*)d_ws;
        unsigned int*   rkT   = (unsigned int*)wsb;
        unsigned short* Wp    = (unsigned short*)(wsb + rkT_bytes);
        __hip_bfloat16* hcatb = (__hip_bfloat16*)(wsb + rkT_bytes + Wp_bytes);

        pack_rkT_kernel<<<768, 256, 0, stream>>>(rkf, rkb, rkT);
        pack_W_kernel<<<13312, 256, 0, stream>>>(W, Wp);

        dim3 g1(3, T, 2);
        proj_kernel<<<g1, 256, 0, stream>>>(x, kf, kb, biasf, biasb, xp);

        gru_scan_v5<<<64, 768, 0, stream>>>(xp, rkT, biasf, biasb, hcatb);

        cls_mfma_kernel<<<2080, 256, 0, stream>>>(hcatb, Wp, bvec, out);
    } else {
        // fp32 fallback (round-2 path)
        float* hcat = (float*)d_ws;     // 10.5 MB
        dim3 g1(3, T, 2);
        proj_kernel<<<g1, 256, 0, stream>>>(x, kf, kb, biasf, biasb, xp);
        gru_scan_f32<<<64, 1024, 0, stream>>>(xp, rkf, rkb, biasf, biasb, hcat);
        cls_f32_kernel<<<13 * 160, 256, 0, stream>>>(hcat, W, bvec, out);
    }
}

// Round 7
// 362.318 us; speedup vs baseline: 5.8147x; 1.4572x over previous
//
#include <hip/hip_runtime.h>
#include <hip/hip_bf16.h>

// Bidirectional GRU (Keras reset_after=True) + dense classifier.
// B=32, T=160, D=512, H=256, C=6625.
// Round 7: proj -> bf16 MFMA (was fp32 VALU-bound, 237 us @ 72% VALUBusy).
//   pack_xb: x -> bf16 time-major [t*32+b][512]; pack_kern: fragment layout.
//   proj_mfma: clone of verified cls_mfma, dir=1 via A-row remap.
//   Scan v5 (weights-in-VGPR) and cls_mfma unchanged from R6.

#define B 32
#define T 160
#define D 512
#define H 256
#define C 6625
#define H3 768
#define NT16 416                  // 52*8 16-col W tiles (padded past 6625)
#define KP_PER_DIR 393216         // 48 nt * 64 kc * 16 col * 8 i (shorts)

typedef __attribute__((ext_vector_type(8))) short short8v;
typedef __attribute__((ext_vector_type(4))) float float4v;

__device__ inline unsigned short f2bf(float v) {
    __hip_bfloat16 b = __float2bfloat16(v);
    return *reinterpret_cast<unsigned short*>(&b);
}
__device__ inline float bflo(unsigned int u) { return __uint_as_float(u << 16); }
__device__ inline float bfhi(unsigned int u) { return __uint_as_float(u & 0xffff0000u); }

#if __has_builtin(__builtin_amdgcn_fdot2_f32_bf16)
#define HAVE_DOT2 1
typedef __attribute__((ext_vector_type(2))) __bf16 bf16x2v;
__device__ inline float dot2bf(unsigned int w, unsigned int h, float acc) {
    return __builtin_amdgcn_fdot2_f32_bf16(
        __builtin_bit_cast(bf16x2v, w), __builtin_bit_cast(bf16x2v, h), acc, false);
}
#else
#define HAVE_DOT2 0
#endif

// ---------------------------------------------------------------- pack rkT
// rkT[dir][g][p][j] = bf16x2( rk[2p][g*256+j], rk[2p+1][g*256+j] )
__global__ __launch_bounds__(256) void pack_rkT_kernel(
    const float* __restrict__ rkf, const float* __restrict__ rkb,
    unsigned int* __restrict__ rkT)
{
    const int idx = blockIdx.x * 256 + threadIdx.x;   // 0..196607
    const int j   = idx & 255;
    const int p   = (idx >> 8) & 127;
    const int g   = (idx >> 15) % 3;
    const int dir = idx / (3 << 15);
    const float* rk = dir ? rkb : rkf;
    const int col = g * 256 + j;
    unsigned int lo = f2bf(rk[(2 * p) * H3 + col]);
    unsigned int hi = f2bf(rk[(2 * p + 1) * H3 + col]);
    rkT[idx] = (hi << 16) | lo;
}

// ---------------------------------------------------------------- pack W
// Wp[nt][kc][col][i] = bf16( W[kc*8+i][nt*16+col] ), zero-padded cols.
__global__ __launch_bounds__(256) void pack_W_kernel(
    const float* __restrict__ W, unsigned short* __restrict__ Wp)
{
    const int idx = blockIdx.x * 256 + threadIdx.x;   // < 416*8192
    const int i   = idx & 7;
    const int col = (idx >> 3) & 15;
    const int kc  = (idx >> 7) & 63;
    const int nt  = idx >> 13;
    const int k = kc * 8 + i;
    const int c = nt * 16 + col;
    const float v = (c < C) ? W[k * C + c] : 0.f;
    Wp[idx] = f2bf(v);
}

// ---------------------------------------------------------------- pack xb
// xb[t*32+b][k] = bf16( x[b][t][k] ) -- time-major, coalesced in k.
__global__ __launch_bounds__(256) void pack_xb_kernel(
    const float* __restrict__ x, unsigned short* __restrict__ xb)
{
    const int idx = blockIdx.x * 256 + threadIdx.x;   // < 2,621,440
    const int k   = idx & 511;
    const int row = idx >> 9;          // t*32+b
    const int t   = row >> 5;
    const int b   = row & 31;
    xb[idx] = f2bf(x[(b * T + t) * 512 + k]);
}

// ---------------------------------------------------------------- pack kern
// kernP[dir][nt48][kc64][col16][i8] = bf16( kern[kc*8+i][nt*16+col] )
__global__ __launch_bounds__(256) void pack_kern_kernel(
    const float* __restrict__ kf, const float* __restrict__ kb,
    unsigned short* __restrict__ kernP)
{
    const int idx = blockIdx.x * 256 + threadIdx.x;   // < 393216
    const int dir = blockIdx.y;
    const float* kern = dir ? kb : kf;
    const int i   = idx & 7;
    const int col = (idx >> 3) & 15;
    const int kc  = (idx >> 7) & 63;
    const int nt  = idx >> 13;         // 0..47
    kernP[dir * KP_PER_DIR + idx] = f2bf(kern[(kc * 8 + i) * H3 + nt * 16 + col]);
}

// ---------------------------------------------------------------- K1: proj (MFMA)
// grid (240, 2): bid.x = ct*40+rt (ct-major for kernP L2 residency), dir=bid.y.
// Block 128 rows x 128 cols, 4 waves 2x2, wave 64x64, K=512.
// A rows: dir=0 -> xb row r; dir=1 -> (159 - r/32)*32 + (r&31).
__global__ __launch_bounds__(256) void proj_mfma_kernel(
    const unsigned short* __restrict__ xb,     // [5120][512] bf16
    const unsigned short* __restrict__ kernP,  // [2][48][64][16][8]
    const float* __restrict__ bias_f,          // [2][H3]
    const float* __restrict__ bias_b,
    float* __restrict__ xp)                    // [2*5120][768] fp32
{
    const int bid = blockIdx.x;
    const int ct  = bid / 40;          // 0..5
    const int rt  = bid % 40;          // 0..39
    const int dir = blockIdx.y;
    const int lane = threadIdx.x & 63;
    const int wid  = threadIdx.x >> 6;
    const int wm = wid >> 1, wn = wid & 1;
    const int rowBase = rt * 128 + wm * 64;
    const int lrow = lane & 15;
    const int lk8  = lane >> 4;        // 0..3
    const float* bias = dir ? bias_b : bias_f;

    float4v acc[4][4];
#pragma unroll
    for (int i = 0; i < 4; ++i)
#pragma unroll
        for (int k = 0; k < 4; ++k) acc[i][k] = (float4v){0.f, 0.f, 0.f, 0.f};

    const short* A  = (const short*)xb;
    const short* Bp = (const short*)(kernP + dir * KP_PER_DIR);
    const int ntBase = ct * 8 + wn * 4;

    // per-fragment A row base (s fixed within a 16-row fragment)
    int arow[4];
#pragma unroll
    for (int mt = 0; mt < 4; ++mt) {
        const int r0 = rowBase + mt * 16;
        const int s  = r0 >> 5;
        arow[mt] = (dir ? (159 - s) : s) * 32 + (r0 & 31);
    }

    for (int k0 = 0; k0 < 512; k0 += 32) {
        short8v aF[4], bF[4];
#pragma unroll
        for (int mt = 0; mt < 4; ++mt)
            aF[mt] = *(const short8v*)&A[(arow[mt] + lrow) * 512 + k0 + lk8 * 8];
#pragma unroll
        for (int ntw = 0; ntw < 4; ++ntw)
            bF[ntw] = *(const short8v*)&Bp[((ntBase + ntw) * 64 + (k0 >> 3) + lk8) * 128 + lrow * 8];
#pragma unroll
        for (int mt = 0; mt < 4; ++mt)
#pragma unroll
            for (int ntw = 0; ntw < 4; ++ntw)
                acc[mt][ntw] = __builtin_amdgcn_mfma_f32_16x16x32_bf16(
                    aF[mt], bF[ntw], acc[mt][ntw], 0, 0, 0);
    }

    const int orow = (lane >> 4) * 4;   // C/D: col=lane&15, row=(lane>>4)*4+reg
#pragma unroll
    for (int ntw = 0; ntw < 4; ++ntw) {
        const int c = (ntBase + ntw) * 16 + lrow;   // 0..767
        const float bc = bias[c];
#pragma unroll
        for (int mt = 0; mt < 4; ++mt)
#pragma unroll
            for (int v = 0; v < 4; ++v)
                xp[(size_t)(dir * 5120 + rowBase + mt * 16 + orow + v) * H3 + c]
                    = acc[mt][ntw][v] + bc;
    }
}

// ---------------------------------------------------------------- K2: scan v5
// grid 64 = (dir<<5)|b, block 768. Thread (g = tid>>8, j = tid&255) owns
// gate-g column j: 256 k of weights = 128 bf16x2 dwords IN VGPRS.
__global__ __launch_bounds__(768, 3) void gru_scan_v5(
    const float* __restrict__ xp,        // [2][T][B][H3] fp32
    const unsigned int* __restrict__ rkT, // [2][3][128][256]
    const float* __restrict__ bias_f,
    const float* __restrict__ bias_b,
    __hip_bfloat16* __restrict__ hcatb)  // [T][B][2H] bf16
{
    const int bid = blockIdx.x;
    const int dir = bid >> 5;
    const int b   = bid & 31;
    const int tid = threadIdx.x;
    const int g   = tid >> 8;          // 0..2 (wave-uniform)
    const int j   = tid & 255;
    const float* bias = dir ? bias_b : bias_f;

    const unsigned int* wsrc = rkT + ((dir * 3 + g) << 15) + j;
    unsigned int w[128];
#pragma unroll
    for (int p = 0; p < 128; ++p) w[p] = wsrc[p << 8];

    float rbz = 0.f, rbr = 0.f, rbh = 0.f;
    if (tid < 256) {
        rbz = bias[H3 + j];
        rbr = bias[H3 + 256 + j];
        rbh = bias[H3 + 512 + j];
    }

    __shared__ float hfp[256];
    __shared__ unsigned int hbf[128];
    __shared__ float sums[2][256];
    if (tid < 256) hfp[tid] = 0.f;
    if (tid < 128) hbf[tid] = 0u;
    __syncthreads();

    for (int s = 0; s < T; ++s) {
        float xz = 0.f, xr = 0.f, xh = 0.f;
        if (tid < 256) {
            const float* xrow = xp + ((dir * T + s) * B + b) * H3;
            xz = xrow[j];
            xr = xrow[256 + j];
            xh = xrow[512 + j];
        }

        float a0 = 0.f, a1 = 0.f, a2 = 0.f, a3 = 0.f;
#if HAVE_DOT2
        {
            const uint4* h4 = (const uint4*)hbf;
#pragma unroll
            for (int q = 0; q < 32; ++q) {
                uint4 hv = h4[q];
                a0 = dot2bf(w[4 * q + 0], hv.x, a0);
                a1 = dot2bf(w[4 * q + 1], hv.y, a1);
                a2 = dot2bf(w[4 * q + 2], hv.z, a2);
                a3 = dot2bf(w[4 * q + 3], hv.w, a3);
                if ((q & 7) == 7) __builtin_amdgcn_sched_barrier(0);
            }
        }
#else
#pragma unroll
        for (int q = 0; q < 32; ++q) {
            float4 h01 = *(const float4*)&hfp[8 * q];
            float4 h23 = *(const float4*)&hfp[8 * q + 4];
            a0 += h01.x * bflo(w[4 * q + 0]) + h01.y * bfhi(w[4 * q + 0]);
            a1 += h01.z * bflo(w[4 * q + 1]) + h01.w * bfhi(w[4 * q + 1]);
            a2 += h23.x * bflo(w[4 * q + 2]) + h23.y * bfhi(w[4 * q + 2]);
            a3 += h23.z * bflo(w[4 * q + 3]) + h23.w * bfhi(w[4 * q + 3]);
            if ((q & 7) == 7) __builtin_amdgcn_sched_barrier(0);
        }
#endif
        const float dot = (a0 + a1) + (a2 + a3);
        if (g > 0) sums[g - 1][j] = dot;
        __syncthreads();

        if (tid < 256) {
            const float sz = dot;
            const float sr = sums[0][j];
            const float sh = sums[1][j];
            const float z  = 1.f / (1.f + __expf(-(xz + sz + rbz)));
            const float r  = 1.f / (1.f + __expf(-(xr + sr + rbr)));
            const float pre = xh + r * (sh + rbh);
            const float e2  = __expf(2.f * pre);
            const float hh  = 1.f - 2.f / (e2 + 1.f);
            const float hn  = z * hfp[j] + (1.f - z) * hh;
            hfp[j] = hn;
#if HAVE_DOT2
            ((unsigned short*)hbf)[j] = f2bf(hn);
#endif
            const int ta = dir ? (T - 1 - s) : s;
            hcatb[(ta * B + b) * 512 + dir * 256 + j] = __float2bfloat16(hn);
        }
        __syncthreads();
    }
}

// ---------------------------------------------------------------- K3: MFMA classifier
__global__ __launch_bounds__(256) void cls_mfma_kernel(
    const __hip_bfloat16* __restrict__ hcatb,
    const unsigned short* __restrict__ Wp,
    const float* __restrict__ bias,
    float* __restrict__ out)
{
    const int bid = blockIdx.x;
    const int ct  = bid / 40;          // 0..51
    const int rt  = bid % 40;          // 0..39
    const int lane = threadIdx.x & 63;
    const int wid  = threadIdx.x >> 6;
    const int wm = wid >> 1, wn = wid & 1;
    const int rowBase = rt * 128 + wm * 64;
    const int lrow = lane & 15;
    const int lk8  = lane >> 4;        // 0..3

    float4v acc[4][4];
#pragma unroll
    for (int i = 0; i < 4; ++i)
#pragma unroll
        for (int k = 0; k < 4; ++k) acc[i][k] = (float4v){0.f, 0.f, 0.f, 0.f};

    const short* A  = (const short*)hcatb;
    const short* Bp = (const short*)Wp;
    const int ntBase = ct * 8 + wn * 4;

    for (int k0 = 0; k0 < 512; k0 += 32) {
        short8v aF[4], bF[4];
#pragma unroll
        for (int mt = 0; mt < 4; ++mt)
            aF[mt] = *(const short8v*)&A[(rowBase + mt * 16 + lrow) * 512 + k0 + lk8 * 8];
#pragma unroll
        for (int ntw = 0; ntw < 4; ++ntw)
            bF[ntw] = *(const short8v*)&Bp[((ntBase + ntw) * 64 + (k0 >> 3) + lk8) * 128 + lrow * 8];
#pragma unroll
        for (int mt = 0; mt < 4; ++mt)
#pragma unroll
            for (int ntw = 0; ntw < 4; ++ntw)
                acc[mt][ntw] = __builtin_amdgcn_mfma_f32_16x16x32_bf16(
                    aF[mt], bF[ntw], acc[mt][ntw], 0, 0, 0);
    }

    const int orow = (lane >> 4) * 4;   // C/D: col=lane&15, row=(lane>>4)*4+reg
#pragma unroll
    for (int ntw = 0; ntw < 4; ++ntw) {
        const int c = (ntBase + ntw) * 16 + lrow;
        if (c >= C) continue;
        const float bc = bias[c];
#pragma unroll
        for (int mt = 0; mt < 4; ++mt)
#pragma unroll
            for (int v = 0; v < 4; ++v)
                out[(size_t)(rowBase + mt * 16 + orow + v) * C + c] = acc[mt][ntw][v] + bc;
    }
}

// ============================ fallback fp32 path (small ws) ============================
__global__ __launch_bounds__(256) void proj_kernel(
    const float* __restrict__ x, const float* __restrict__ kf,
    const float* __restrict__ kb, const float* __restrict__ bias_f,
    const float* __restrict__ bias_b, float* __restrict__ xp)
{
    const int ct  = blockIdx.x;
    const int s   = blockIdx.y;
    const int dir = blockIdx.z;
    const int tid = threadIdx.x;
    const int t   = dir ? (T - 1 - s) : s;
    const float* kern = dir ? kb : kf;
    const float* bias = dir ? bias_b : bias_f;

    __shared__ float xs[32 * 512];
    for (int it = 0; it < 16; ++it) {
        int v = it * 256 + tid, row = v >> 7, k4 = v & 127;
        *(float4*)&xs[(row << 9) + (k4 << 2)] =
            *(const float4*)&x[((row * T + t) << 9) + (k4 << 2)];
    }
    __syncthreads();

    const int col = ct * 256 + tid;
    float acc[32];
#pragma unroll
    for (int r = 0; r < 32; ++r) acc[r] = 0.f;
    for (int k = 0; k < 512; k += 4) {
        float w0 = kern[(k + 0) * H3 + col];
        float w1 = kern[(k + 1) * H3 + col];
        float w2 = kern[(k + 2) * H3 + col];
        float w3 = kern[(k + 3) * H3 + col];
#pragma unroll
        for (int r = 0; r < 32; ++r) {
            float4 xv = *(const float4*)&xs[(r << 9) + k];
            acc[r] += xv.x * w0 + xv.y * w1 + xv.z * w2 + xv.w * w3;
        }
    }
    const float bb = bias[col];
    for (int r = 0; r < 32; ++r)
        xp[((dir * T + s) * B + r) * H3 + col] = acc[r] + bb;
}

__global__ __launch_bounds__(1024) void gru_scan_f32(
    const float* __restrict__ xp,
    const float* __restrict__ rk_f, const float* __restrict__ rk_b,
    const float* __restrict__ bias_f, const float* __restrict__ bias_b,
    float* __restrict__ hcat)
{
    const int bid = blockIdx.x;
    const int dir = bid >> 5;
    const int b   = bid & 31;
    const int tid = threadIdx.x;
    const int kg  = tid >> 8;
    const int j   = tid & 255;
    const int k0  = kg << 6;
    const float* rk   = dir ? rk_b : rk_f;
    const float* bias = dir ? bias_b : bias_f;
    const float rbz = bias[H3 + j];
    const float rbr = bias[H3 + 256 + j];
    const float rbh = bias[H3 + 512 + j];

    __shared__ float h[256];
    __shared__ float part[3][4][256];
    if (tid < 256) h[tid] = 0.f;
    __syncthreads();

    for (int s = 0; s < T; ++s) {
        const float* xrow = xp + ((dir * T + s) * B + b) * H3;
        float az = 0.f, ar = 0.f, ah = 0.f;
#pragma unroll 4
        for (int k = k0; k < k0 + 64; k += 4) {
            float4 h4 = *(const float4*)&h[k];
            const float* rkp = rk + k * H3 + j;
            az += h4.x * rkp[0];       ar += h4.x * rkp[256];       ah += h4.x * rkp[512];
            az += h4.y * rkp[H3];      ar += h4.y * rkp[H3+256];    ah += h4.y * rkp[H3+512];
            az += h4.z * rkp[2*H3];    ar += h4.z * rkp[2*H3+256];  ah += h4.z * rkp[2*H3+512];
            az += h4.w * rkp[3*H3];    ar += h4.w * rkp[3*H3+256];  ah += h4.w * rkp[3*H3+512];
        }
        part[0][kg][j] = az; part[1][kg][j] = ar; part[2][kg][j] = ah;
        __syncthreads();
        if (tid < 256) {
            const float sz = part[0][0][tid]+part[0][1][tid]+part[0][2][tid]+part[0][3][tid];
            const float sr = part[1][0][tid]+part[1][1][tid]+part[1][2][tid]+part[1][3][tid];
            const float sh = part[2][0][tid]+part[2][1][tid]+part[2][2][tid]+part[2][3][tid];
            const float xz = xrow[tid], xr = xrow[256+tid], xh = xrow[512+tid];
            const float z  = 1.f / (1.f + __expf(-(xz + sz + rbz)));
            const float r  = 1.f / (1.f + __expf(-(xr + sr + rbr)));
            const float pre = xh + r * (sh + rbh);
            const float e2  = __expf(2.f * pre);
            const float hh  = 1.f - 2.f / (e2 + 1.f);
            const float hn  = z * h[tid] + (1.f - z) * hh;
            h[tid] = hn;
            const int ta = dir ? (T - 1 - s) : s;
            hcat[(ta * B + b) * (2 * H) + dir * H + tid] = hn;
        }
        __syncthreads();
    }
}

__global__ __launch_bounds__(256) void cls_f32_kernel(
    const float* __restrict__ hcat, const float* __restrict__ W,
    const float* __restrict__ bias, float* __restrict__ out)
{
    const int bid = blockIdx.x;
    const int ct  = bid / 160;
    const int rt  = bid % 160;
    const int tid = threadIdx.x;
    const int r0  = rt * 32;

    __shared__ float hs[32 * 512];
    for (int it = 0; it < 16; ++it) {
        int v = it * 256 + tid, row = v >> 7, k4 = v & 127;
        *(float4*)&hs[(row << 9) + (k4 << 2)] =
            *(const float4*)&hcat[((r0 + row) << 9) + (k4 << 2)];
    }
    __syncthreads();

    const int c0 = ct * 512 + tid;
    const int c1 = c0 + 256;
    const bool v1 = (c1 < C);
    float acc0[32], acc1[32];
#pragma unroll
    for (int r = 0; r < 32; ++r) { acc0[r] = 0.f; acc1[r] = 0.f; }
    for (int k = 0; k < 512; k += 4) {
        const float* wp = W + k * C;
        float w00 = wp[c0], w01 = wp[C+c0], w02 = wp[2*C+c0], w03 = wp[3*C+c0];
        float w10 = v1 ? wp[c1] : 0.f, w11 = v1 ? wp[C+c1] : 0.f;
        float w12 = v1 ? wp[2*C+c1] : 0.f, w13 = v1 ? wp[3*C+c1] : 0.f;
#pragma unroll
        for (int r = 0; r < 32; ++r) {
            float4 hv = *(const float4*)&hs[(r << 9) + k];
            acc0[r] += hv.x*w00 + hv.y*w01 + hv.z*w02 + hv.w*w03;
            acc1[r] += hv.x*w10 + hv.y*w11 + hv.z*w12 + hv.w*w13;
        }
    }
    const float b0 = bias[c0];
    const float b1 = v1 ? bias[c1] : 0.f;
    for (int r = 0; r < 32; ++r) {
        out[(size_t)(r0+r)*C + c0] = acc0[r] + b0;
        if (v1) out[(size_t)(r0+r)*C + c1] = acc1[r] + b1;
    }
}

// ---------------------------------------------------------------- launch
extern "C" void kernel_launch(void* const* d_in, const int* in_sizes, int n_in,
                              void* d_out, int out_size, void* d_ws, size_t ws_size,
                              hipStream_t stream) {
    const float* x     = (const float*)d_in[0];
    const float* kf    = (const float*)d_in[1];
    const float* rkf   = (const float*)d_in[2];
    const float* biasf = (const float*)d_in[3];
    const float* kb    = (const float*)d_in[4];
    const float* rkb   = (const float*)d_in[5];
    const float* biasb = (const float*)d_in[6];
    const float* W     = (const float*)d_in[7];
    const float* bvec  = (const float*)d_in[8];
    float* out = (float*)d_out;

    const size_t rkT_bytes   = (size_t)2 * 3 * 128 * 256 * 4;     //   786,432
    const size_t Wp_bytes    = (size_t)NT16 * 8192 * 2;           // 6,815,744
    const size_t hcatb_bytes = (size_t)T * B * 2 * H * 2;         // 5,242,880
    const size_t planA_bytes = rkT_bytes + Wp_bytes + hcatb_bytes;

    // d_out (135.7 MB) carved up; all regions dead before cls writes out:
    //   [0, 31.5 MB)        xp   [2*5120][768] fp32
    //   [31.5, 36.7 MB)     xb   [5120][512] bf16
    //   [36.7, 38.3 MB)     kernP [2][393216] bf16
    float*          xp    = out;
    unsigned short* xb    = (unsigned short*)((char*)out + (size_t)2 * 5120 * H3 * 4);
    unsigned short* kernP = (unsigned short*)((char*)xb + (size_t)5120 * 512 * 2);

    if (ws_size >= planA_bytes) {
        char* wsb = (char*)d_ws;
        unsigned int*   rkT   = (unsigned int*)wsb;
        unsigned short* Wp    = (unsigned short*)(wsb + rkT_bytes);
        __hip_bfloat16* hcatb = (__hip_bfloat16*)(wsb + rkT_bytes + Wp_bytes);

        pack_rkT_kernel<<<768, 256, 0, stream>>>(rkf, rkb, rkT);
        pack_W_kernel<<<13312, 256, 0, stream>>>(W, Wp);
        pack_xb_kernel<<<10240, 256, 0, stream>>>(x, xb);
        pack_kern_kernel<<<dim3(1536, 2), 256, 0, stream>>>(kf, kb, kernP);

        proj_mfma_kernel<<<dim3(240, 2), 256, 0, stream>>>(xb, kernP, biasf, biasb, xp);

        gru_scan_v5<<<64, 768, 0, stream>>>(xp, rkT, biasf, biasb, hcatb);

        cls_mfma_kernel<<<2080, 256, 0, stream>>>(hcatb, Wp, bvec, out);
    } else {
        // fp32 fallback (round-2 path)
        float* hcat = (float*)d_ws;     // 10.5 MB
        dim3 g1(3, T, 2);
        proj_kernel<<<g1, 256, 0, stream>>>(x, kf, kb, biasf, biasb, xp);
        gru_scan_f32<<<64, 1024, 0, stream>>>(xp, rkf, rkb, biasf, biasb, hcat);
        cls_f32_kernel<<<13 * 160, 256, 0, stream>>>(hcat, W, bvec, out);
    }
}

// Round 8
// 336.916 us; speedup vs baseline: 6.2531x; 1.0754x over previous
//
#include <hip/hip_runtime.h>
#include <hip/hip_bf16.h>

// Bidirectional GRU (Keras reset_after=True) + dense classifier.
// B=32, T=160, D=512, H=256, C=6625.
// Round 8: scan v6 -- per-step h@rk via MFMA (M=16, h row-replicated; result
//   from row 0). Wave w holds B-frags for its 4 n-tiles in 128 regs (AGPR-
//   native for MFMA, no v_accvgpr_read tax that v5's dot2 path paid).
//   12 waves x 4 nt x 16 = 768 gate cols. Same 64-WG no-cross-sync structure.
//   proj_mfma / cls_mfma / packs unchanged from R7.

#define B 32
#define T 160
#define D 512
#define H 256
#define C 6625
#define H3 768
#define NT16 416                  // 52*8 16-col W tiles (padded past 6625)
#define KP_PER_DIR 393216         // proj kernel pack: 48 nt * 64 kc * 16 * 8
#define RKB_PER_DIR 196608        // scan rk pack: 48 nt * 32 kc * 16 * 8

typedef __attribute__((ext_vector_type(8))) short short8v;
typedef __attribute__((ext_vector_type(4))) float float4v;

__device__ inline unsigned short f2bf(float v) {
    __hip_bfloat16 b = __float2bfloat16(v);
    return *reinterpret_cast<unsigned short*>(&b);
}

// ---------------------------------------------------------------- pack rkB (scan B-fragments)
// rkB[dir][nt48][kc32][col16][i8] = bf16( rk[kc*8+i][nt*16+col] )
__global__ __launch_bounds__(256) void pack_rkB_kernel(
    const float* __restrict__ rkf, const float* __restrict__ rkb,
    unsigned short* __restrict__ rkB)
{
    const int idx = blockIdx.x * 256 + threadIdx.x;   // < 196608
    const int dir = blockIdx.y;
    const float* rk = dir ? rkb : rkf;
    const int i   = idx & 7;
    const int col = (idx >> 3) & 15;
    const int kc  = (idx >> 7) & 31;
    const int nt  = idx >> 12;         // 0..47
    rkB[dir * RKB_PER_DIR + idx] = f2bf(rk[(kc * 8 + i) * H3 + nt * 16 + col]);
}

// ---------------------------------------------------------------- pack W
// Wp[nt][kc][col][i] = bf16( W[kc*8+i][nt*16+col] ), zero-padded cols.
__global__ __launch_bounds__(256) void pack_W_kernel(
    const float* __restrict__ W, unsigned short* __restrict__ Wp)
{
    const int idx = blockIdx.x * 256 + threadIdx.x;   // < 416*8192
    const int i   = idx & 7;
    const int col = (idx >> 3) & 15;
    const int kc  = (idx >> 7) & 63;
    const int nt  = idx >> 13;
    const int k = kc * 8 + i;
    const int c = nt * 16 + col;
    const float v = (c < C) ? W[k * C + c] : 0.f;
    Wp[idx] = f2bf(v);
}

// ---------------------------------------------------------------- pack xb
// xb[t*32+b][k] = bf16( x[b][t][k] ) -- time-major, coalesced in k.
__global__ __launch_bounds__(256) void pack_xb_kernel(
    const float* __restrict__ x, unsigned short* __restrict__ xb)
{
    const int idx = blockIdx.x * 256 + threadIdx.x;   // < 2,621,440
    const int k   = idx & 511;
    const int row = idx >> 9;          // t*32+b
    const int t   = row >> 5;
    const int b   = row & 31;
    xb[idx] = f2bf(x[(b * T + t) * 512 + k]);
}

// ---------------------------------------------------------------- pack kern
// kernP[dir][nt48][kc64][col16][i8] = bf16( kern[kc*8+i][nt*16+col] )
__global__ __launch_bounds__(256) void pack_kern_kernel(
    const float* __restrict__ kf, const float* __restrict__ kb,
    unsigned short* __restrict__ kernP)
{
    const int idx = blockIdx.x * 256 + threadIdx.x;   // < 393216
    const int dir = blockIdx.y;
    const float* kern = dir ? kb : kf;
    const int i   = idx & 7;
    const int col = (idx >> 3) & 15;
    const int kc  = (idx >> 7) & 63;
    const int nt  = idx >> 13;         // 0..47
    kernP[dir * KP_PER_DIR + idx] = f2bf(kern[(kc * 8 + i) * H3 + nt * 16 + col]);
}

// ---------------------------------------------------------------- K1: proj (MFMA)
__global__ __launch_bounds__(256) void proj_mfma_kernel(
    const unsigned short* __restrict__ xb,     // [5120][512] bf16
    const unsigned short* __restrict__ kernP,  // [2][48][64][16][8]
    const float* __restrict__ bias_f,          // [2][H3]
    const float* __restrict__ bias_b,
    float* __restrict__ xp)                    // [2*5120][768] fp32
{
    const int bid = blockIdx.x;
    const int ct  = bid / 40;          // 0..5
    const int rt  = bid % 40;          // 0..39
    const int dir = blockIdx.y;
    const int lane = threadIdx.x & 63;
    const int wid  = threadIdx.x >> 6;
    const int wm = wid >> 1, wn = wid & 1;
    const int rowBase = rt * 128 + wm * 64;
    const int lrow = lane & 15;
    const int lk8  = lane >> 4;        // 0..3
    const float* bias = dir ? bias_b : bias_f;

    float4v acc[4][4];
#pragma unroll
    for (int i = 0; i < 4; ++i)
#pragma unroll
        for (int k = 0; k < 4; ++k) acc[i][k] = (float4v){0.f, 0.f, 0.f, 0.f};

    const short* A  = (const short*)xb;
    const short* Bp = (const short*)(kernP + dir * KP_PER_DIR);
    const int ntBase = ct * 8 + wn * 4;

    int arow[4];
#pragma unroll
    for (int mt = 0; mt < 4; ++mt) {
        const int r0 = rowBase + mt * 16;
        const int s  = r0 >> 5;
        arow[mt] = (dir ? (159 - s) : s) * 32 + (r0 & 31);
    }

    for (int k0 = 0; k0 < 512; k0 += 32) {
        short8v aF[4], bF[4];
#pragma unroll
        for (int mt = 0; mt < 4; ++mt)
            aF[mt] = *(const short8v*)&A[(arow[mt] + lrow) * 512 + k0 + lk8 * 8];
#pragma unroll
        for (int ntw = 0; ntw < 4; ++ntw)
            bF[ntw] = *(const short8v*)&Bp[((ntBase + ntw) * 64 + (k0 >> 3) + lk8) * 128 + lrow * 8];
#pragma unroll
        for (int mt = 0; mt < 4; ++mt)
#pragma unroll
            for (int ntw = 0; ntw < 4; ++ntw)
                acc[mt][ntw] = __builtin_amdgcn_mfma_f32_16x16x32_bf16(
                    aF[mt], bF[ntw], acc[mt][ntw], 0, 0, 0);
    }

    const int orow = (lane >> 4) * 4;   // C/D: col=lane&15, row=(lane>>4)*4+reg
#pragma unroll
    for (int ntw = 0; ntw < 4; ++ntw) {
        const int c = (ntBase + ntw) * 16 + lrow;   // 0..767
        const float bc = bias[c];
#pragma unroll
        for (int mt = 0; mt < 4; ++mt)
#pragma unroll
            for (int v = 0; v < 4; ++v)
                xp[(size_t)(dir * 5120 + rowBase + mt * 16 + orow + v) * H3 + c]
                    = acc[mt][ntw][v] + bc;
    }
}

// ---------------------------------------------------------------- K2: scan v6 (MFMA)
// grid 64 = (dir<<5)|b, block 768 = 12 waves. Wave w owns gate cols
// [w*64, w*64+64) = 4 n-tiles; B-frags (4nt x 8kk x 4regs = 128 regs) loaded
// once. Per step: A = h row-replicated (all 16 rows identical -> D rows all
// equal the dot; read row 0 = lanes 0..15, reg 0). sums LDS -> gate math by
// tid<256 -> h update. 2 barriers/step.
__global__ __launch_bounds__(768, 3) void gru_scan_v6(
    const float* __restrict__ xp,          // [2][T][B][H3] fp32
    const unsigned short* __restrict__ rkB, // [2][48][32][16][8]
    const float* __restrict__ bias_f,
    const float* __restrict__ bias_b,
    __hip_bfloat16* __restrict__ hcatb)    // [T][B][2H] bf16
{
    const int bid = blockIdx.x;
    const int dir = bid >> 5;
    const int b   = bid & 31;
    const int tid = threadIdx.x;
    const int wv  = tid >> 6;          // 0..11
    const int lane = tid & 63;
    const int lrow = lane & 15;
    const int lk8  = lane >> 4;        // 0..3
    const int j   = tid & 255;
    const float* bias = dir ? bias_b : bias_f;
    const short* Bp = (const short*)(rkB + (size_t)dir * RKB_PER_DIR);

    // ---- one-time: B fragments into regs (MFMA reads AGPR natively) ----
    short8v bw[32];                    // [nt 0..3][kk 0..7]
#pragma unroll
    for (int i = 0; i < 4; ++i)
#pragma unroll
        for (int kk = 0; kk < 8; ++kk)
            bw[i * 8 + kk] = *(const short8v*)
                &Bp[(((wv * 4 + i) * 32) + kk * 4 + lk8) * 128 + lrow * 8];

    float rbz = 0.f, rbr = 0.f, rbh = 0.f;
    if (tid < 256) {
        rbz = bias[H3 + j];
        rbr = bias[H3 + 256 + j];
        rbh = bias[H3 + 512 + j];
    }

    __shared__ float hfp[256];                         // fp32 h (for z*h_old)
    __shared__ __align__(16) unsigned short hus[256];  // bf16 h (A operand)
    __shared__ float sums[768];                        // gate dots
    if (tid < 256) { hfp[tid] = 0.f; hus[tid] = 0; }
    __syncthreads();

    for (int s = 0; s < T; ++s) {
        float xz = 0.f, xr = 0.f, xh = 0.f;
        if (tid < 256) {               // issue early; hides under MFMA phase
            const float* xrow = xp + ((dir * T + s) * B + b) * H3;
            xz = xrow[j];
            xr = xrow[256 + j];
            xh = xrow[512 + j];
        }

        float4v a0 = {0.f,0.f,0.f,0.f}, a1 = {0.f,0.f,0.f,0.f};
        float4v a2 = {0.f,0.f,0.f,0.f}, a3 = {0.f,0.f,0.f,0.f};
#pragma unroll
        for (int kk = 0; kk < 8; ++kk) {
            // row-replicated A: every lane reads its k-chunk of h (addr
            // independent of lrow -> 4-way broadcast read)
            short8v aF = *(const short8v*)&hus[kk * 32 + lk8 * 8];
            a0 = __builtin_amdgcn_mfma_f32_16x16x32_bf16(aF, bw[0 * 8 + kk], a0, 0, 0, 0);
            a1 = __builtin_amdgcn_mfma_f32_16x16x32_bf16(aF, bw[1 * 8 + kk], a1, 0, 0, 0);
            a2 = __builtin_amdgcn_mfma_f32_16x16x32_bf16(aF, bw[2 * 8 + kk], a2, 0, 0, 0);
            a3 = __builtin_amdgcn_mfma_f32_16x16x32_bf16(aF, bw[3 * 8 + kk], a3, 0, 0, 0);
        }
        if (lane < 16) {               // row 0 = lanes 0..15, reg 0
            sums[(wv * 4 + 0) * 16 + lane] = a0[0];
            sums[(wv * 4 + 1) * 16 + lane] = a1[0];
            sums[(wv * 4 + 2) * 16 + lane] = a2[0];
            sums[(wv * 4 + 3) * 16 + lane] = a3[0];
        }
        __syncthreads();               // sums visible

        if (tid < 256) {
            const float sz = sums[j];
            const float sr = sums[256 + j];
            const float sh = sums[512 + j];
            const float z  = 1.f / (1.f + __expf(-(xz + sz + rbz)));
            const float r  = 1.f / (1.f + __expf(-(xr + sr + rbr)));
            const float pre = xh + r * (sh + rbh);
            const float e2  = __expf(2.f * pre);
            const float hh  = 1.f - 2.f / (e2 + 1.f);   // tanh, inf-safe
            const float hn  = z * hfp[j] + (1.f - z) * hh;
            hfp[j] = hn;
            hus[j] = f2bf(hn);
            const int ta = dir ? (T - 1 - s) : s;
            hcatb[(ta * B + b) * 512 + dir * 256 + j] = __float2bfloat16(hn);
        }
        __syncthreads();               // h_{s+1} ready
    }
}

// ---------------------------------------------------------------- K3: MFMA classifier
__global__ __launch_bounds__(256) void cls_mfma_kernel(
    const __hip_bfloat16* __restrict__ hcatb,
    const unsigned short* __restrict__ Wp,
    const float* __restrict__ bias,
    float* __restrict__ out)
{
    const int bid = blockIdx.x;
    const int ct  = bid / 40;          // 0..51
    const int rt  = bid % 40;          // 0..39
    const int lane = threadIdx.x & 63;
    const int wid  = threadIdx.x >> 6;
    const int wm = wid >> 1, wn = wid & 1;
    const int rowBase = rt * 128 + wm * 64;
    const int lrow = lane & 15;
    const int lk8  = lane >> 4;        // 0..3

    float4v acc[4][4];
#pragma unroll
    for (int i = 0; i < 4; ++i)
#pragma unroll
        for (int k = 0; k < 4; ++k) acc[i][k] = (float4v){0.f, 0.f, 0.f, 0.f};

    const short* A  = (const short*)hcatb;
    const short* Bp = (const short*)Wp;
    const int ntBase = ct * 8 + wn * 4;

    for (int k0 = 0; k0 < 512; k0 += 32) {
        short8v aF[4], bF[4];
#pragma unroll
        for (int mt = 0; mt < 4; ++mt)
            aF[mt] = *(const short8v*)&A[(rowBase + mt * 16 + lrow) * 512 + k0 + lk8 * 8];
#pragma unroll
        for (int ntw = 0; ntw < 4; ++ntw)
            bF[ntw] = *(const short8v*)&Bp[((ntBase + ntw) * 64 + (k0 >> 3) + lk8) * 128 + lrow * 8];
#pragma unroll
        for (int mt = 0; mt < 4; ++mt)
#pragma unroll
            for (int ntw = 0; ntw < 4; ++ntw)
                acc[mt][ntw] = __builtin_amdgcn_mfma_f32_16x16x32_bf16(
                    aF[mt], bF[ntw], acc[mt][ntw], 0, 0, 0);
    }

    const int orow = (lane >> 4) * 4;   // C/D: col=lane&15, row=(lane>>4)*4+reg
#pragma unroll
    for (int ntw = 0; ntw < 4; ++ntw) {
        const int c = (ntBase + ntw) * 16 + lrow;
        if (c >= C) continue;
        const float bc = bias[c];
#pragma unroll
        for (int mt = 0; mt < 4; ++mt)
#pragma unroll
            for (int v = 0; v < 4; ++v)
                out[(size_t)(rowBase + mt * 16 + orow + v) * C + c] = acc[mt][ntw][v] + bc;
    }
}

// ============================ fallback fp32 path (small ws) ============================
__global__ __launch_bounds__(256) void proj_kernel(
    const float* __restrict__ x, const float* __restrict__ kf,
    const float* __restrict__ kb, const float* __restrict__ bias_f,
    const float* __restrict__ bias_b, float* __restrict__ xp)
{
    const int ct  = blockIdx.x;
    const int s   = blockIdx.y;
    const int dir = blockIdx.z;
    const int tid = threadIdx.x;
    const int t   = dir ? (T - 1 - s) : s;
    const float* kern = dir ? kb : kf;
    const float* bias = dir ? bias_b : bias_f;

    __shared__ float xs[32 * 512];
    for (int it = 0; it < 16; ++it) {
        int v = it * 256 + tid, row = v >> 7, k4 = v & 127;
        *(float4*)&xs[(row << 9) + (k4 << 2)] =
            *(const float4*)&x[((row * T + t) << 9) + (k4 << 2)];
    }
    __syncthreads();

    const int col = ct * 256 + tid;
    float acc[32];
#pragma unroll
    for (int r = 0; r < 32; ++r) acc[r] = 0.f;
    for (int k = 0; k < 512; k += 4) {
        float w0 = kern[(k + 0) * H3 + col];
        float w1 = kern[(k + 1) * H3 + col];
        float w2 = kern[(k + 2) * H3 + col];
        float w3 = kern[(k + 3) * H3 + col];
#pragma unroll
        for (int r = 0; r < 32; ++r) {
            float4 xv = *(const float4*)&xs[(r << 9) + k];
            acc[r] += xv.x * w0 + xv.y * w1 + xv.z * w2 + xv.w * w3;
        }
    }
    const float bb = bias[col];
    for (int r = 0; r < 32; ++r)
        xp[((dir * T + s) * B + r) * H3 + col] = acc[r] + bb;
}

__global__ __launch_bounds__(1024) void gru_scan_f32(
    const float* __restrict__ xp,
    const float* __restrict__ rk_f, const float* __restrict__ rk_b,
    const float* __restrict__ bias_f, const float* __restrict__ bias_b,
    float* __restrict__ hcat)
{
    const int bid = blockIdx.x;
    const int dir = bid >> 5;
    const int b   = bid & 31;
    const int tid = threadIdx.x;
    const int kg  = tid >> 8;
    const int j   = tid & 255;
    const int k0  = kg << 6;
    const float* rk   = dir ? rk_b : rk_f;
    const float* bias = dir ? bias_b : bias_f;
    const float rbz = bias[H3 + j];
    const float rbr = bias[H3 + 256 + j];
    const float rbh = bias[H3 + 512 + j];

    __shared__ float h[256];
    __shared__ float part[3][4][256];
    if (tid < 256) h[tid] = 0.f;
    __syncthreads();

    for (int s = 0; s < T; ++s) {
        const float* xrow = xp + ((dir * T + s) * B + b) * H3;
        float az = 0.f, ar = 0.f, ah = 0.f;
#pragma unroll 4
        for (int k = k0; k < k0 + 64; k += 4) {
            float4 h4 = *(const float4*)&h[k];
            const float* rkp = rk + k * H3 + j;
            az += h4.x * rkp[0];       ar += h4.x * rkp[256];       ah += h4.x * rkp[512];
            az += h4.y * rkp[H3];      ar += h4.y * rkp[H3+256];    ah += h4.y * rkp[H3+512];
            az += h4.z * rkp[2*H3];    ar += h4.z * rkp[2*H3+256];  ah += h4.z * rkp[2*H3+512];
            az += h4.w * rkp[3*H3];    ar += h4.w * rkp[3*H3+256];  ah += h4.w * rkp[3*H3+512];
        }
        part[0][kg][j] = az; part[1][kg][j] = ar; part[2][kg][j] = ah;
        __syncthreads();
        if (tid < 256) {
            const float sz = part[0][0][tid]+part[0][1][tid]+part[0][2][tid]+part[0][3][tid];
            const float sr = part[1][0][tid]+part[1][1][tid]+part[1][2][tid]+part[1][3][tid];
            const float sh = part[2][0][tid]+part[2][1][tid]+part[2][2][tid]+part[2][3][tid];
            const float xz = xrow[tid], xr = xrow[256+tid], xh = xrow[512+tid];
            const float z  = 1.f / (1.f + __expf(-(xz + sz + rbz)));
            const float r  = 1.f / (1.f + __expf(-(xr + sr + rbr)));
            const float pre = xh + r * (sh + rbh);
            const float e2  = __expf(2.f * pre);
            const float hh  = 1.f - 2.f / (e2 + 1.f);
            const float hn  = z * h[tid] + (1.f - z) * hh;
            h[tid] = hn;
            const int ta = dir ? (T - 1 - s) : s;
            hcat[(ta * B + b) * (2 * H) + dir * H + tid] = hn;
        }
        __syncthreads();
    }
}

__global__ __launch_bounds__(256) void cls_f32_kernel(
    const float* __restrict__ hcat, const float* __restrict__ W,
    const float* __restrict__ bias, float* __restrict__ out)
{
    const int bid = blockIdx.x;
    const int ct  = bid / 160;
    const int rt  = bid % 160;
    const int tid = threadIdx.x;
    const int r0  = rt * 32;

    __shared__ float hs[32 * 512];
    for (int it = 0; it < 16; ++it) {
        int v = it * 256 + tid, row = v >> 7, k4 = v & 127;
        *(float4*)&hs[(row << 9) + (k4 << 2)] =
            *(const float4*)&hcat[((r0 + row) << 9) + (k4 << 2)];
    }
    __syncthreads();

    const int c0 = ct * 512 + tid;
    const int c1 = c0 + 256;
    const bool v1 = (c1 < C);
    float acc0[32], acc1[32];
#pragma unroll
    for (int r = 0; r < 32; ++r) { acc0[r] = 0.f; acc1[r] = 0.f; }
    for (int k = 0; k < 512; k += 4) {
        const float* wp = W + k * C;
        float w00 = wp[c0], w01 = wp[C+c0], w02 = wp[2*C+c0], w03 = wp[3*C+c0];
        float w10 = v1 ? wp[c1] : 0.f, w11 = v1 ? wp[C+c1] : 0.f;
        float w12 = v1 ? wp[2*C+c1] : 0.f, w13 = v1 ? wp[3*C+c1] : 0.f;
#pragma unroll
        for (int r = 0; r < 32; ++r) {
            float4 hv = *(const float4*)&hs[(r << 9) + k];
            acc0[r] += hv.x*w00 + hv.y*w01 + hv.z*w02 + hv.w*w03;
            acc1[r] += hv.x*w10 + hv.y*w11 + hv.z*w12 + hv.w*w13;
        }
    }
    const float b0 = bias[c0];
    const float b1 = v1 ? bias[c1] : 0.f;
    for (int r = 0; r < 32; ++r) {
        out[(size_t)(r0+r)*C + c0] = acc0[r] + b0;
        if (v1) out[(size_t)(r0+r)*C + c1] = acc1[r] + b1;
    }
}

// ---------------------------------------------------------------- launch
extern "C" void kernel_launch(void* const* d_in, const int* in_sizes, int n_in,
                              void* d_out, int out_size, void* d_ws, size_t ws_size,
                              hipStream_t stream) {
    const float* x     = (const float*)d_in[0];
    const float* kf    = (const float*)d_in[1];
    const float* rkf   = (const float*)d_in[2];
    const float* biasf = (const float*)d_in[3];
    const float* kb    = (const float*)d_in[4];
    const float* rkb   = (const float*)d_in[5];
    const float* biasb = (const float*)d_in[6];
    const float* W     = (const float*)d_in[7];
    const float* bvec  = (const float*)d_in[8];
    float* out = (float*)d_out;

    const size_t rkB_bytes   = (size_t)2 * RKB_PER_DIR * 2;       //   786,432
    const size_t Wp_bytes    = (size_t)NT16 * 8192 * 2;           // 6,815,744
    const size_t hcatb_bytes = (size_t)T * B * 2 * H * 2;         // 5,242,880
    const size_t planA_bytes = rkB_bytes + Wp_bytes + hcatb_bytes;

    // d_out (135.7 MB) carved up; all regions dead before cls writes out:
    //   [0, 31.5 MB)        xp    [2*5120][768] fp32
    //   [31.5, 36.7 MB)     xb    [5120][512] bf16
    //   [36.7, 38.3 MB)     kernP [2][393216] bf16
    float*          xp    = out;
    unsigned short* xb    = (unsigned short*)((char*)out + (size_t)2 * 5120 * H3 * 4);
    unsigned short* kernP = (unsigned short*)((char*)xb + (size_t)5120 * 512 * 2);

    if (ws_size >= planA_bytes) {
        char* wsb = (char*)d_ws;
        unsigned short* rkB   = (unsigned short*)wsb;
        unsigned short* Wp    = (unsigned short*)(wsb + rkB_bytes);
        __hip_bfloat16* hcatb = (__hip_bfloat16*)(wsb + rkB_bytes + Wp_bytes);

        pack_rkB_kernel<<<dim3(768, 2), 256, 0, stream>>>(rkf, rkb, rkB);
        pack_W_kernel<<<13312, 256, 0, stream>>>(W, Wp);
        pack_xb_kernel<<<10240, 256, 0, stream>>>(x, xb);
        pack_kern_kernel<<<dim3(1536, 2), 256, 0, stream>>>(kf, kb, kernP);

        proj_mfma_kernel<<<dim3(240, 2), 256, 0, stream>>>(xb, kernP, biasf, biasb, xp);

        gru_scan_v6<<<64, 768, 0, stream>>>(xp, rkB, biasf, biasb, hcatb);

        cls_mfma_kernel<<<2080, 256, 0, stream>>>(hcatb, Wp, bvec, out);
    } else {
        // fp32 fallback (round-2 path)
        float* hcat = (float*)d_ws;     // 10.5 MB
        dim3 g1(3, T, 2);
        proj_kernel<<<g1, 256, 0, stream>>>(x, kf, kb, biasf, biasb, xp);
        gru_scan_f32<<<64, 1024, 0, stream>>>(xp, rkf, rkb, biasf, biasb, hcat);
        cls_f32_kernel<<<13 * 160, 256, 0, stream>>>(hcat, W, bvec, out);
    }
}

// Round 9
// 319.248 us; speedup vs baseline: 6.5992x; 1.0553x over previous
//
#include <hip/hip_runtime.h>
#include <hip/hip_bf16.h>

// Bidirectional GRU (Keras reset_after=True) + dense classifier.
// B=32, T=160, D=512, H=256, C=6625.
// Round 9: cls v2 -- 128x256 tile, A staged in 128KB LDS with XOR swizzle
//   (row-stride 1024B would be a 16-way bank conflict without it), B global
//   ct-major. xp -> bf16 (proj epilogue + scan load): halves scan HBM bytes.
//   Scan v6 (MFMA, reg-resident B) structure unchanged -- it is MFMA-issue
//   bound at ~776 cyc/step on 64 CUs (384 frags fixed by 768n x 256k shape).

#define B 32
#define T 160
#define D 512
#define H 256
#define C 6625
#define H3 768
#define NT16 416                  // 26*16 16-col W tiles (padded past 6625)
#define KP_PER_DIR 393216         // proj kernel pack: 48 nt * 64 kc * 16 * 8
#define RKB_PER_DIR 196608        // scan rk pack: 48 nt * 32 kc * 16 * 8

typedef __attribute__((ext_vector_type(8))) short short8v;
typedef __attribute__((ext_vector_type(4))) float float4v;

__device__ inline unsigned short f2bf(float v) {
    __hip_bfloat16 b = __float2bfloat16(v);
    return *reinterpret_cast<unsigned short*>(&b);
}
__device__ inline float bf2f(unsigned short u) {
    return __uint_as_float((unsigned int)u << 16);
}

// ---------------------------------------------------------------- pack rkB (scan B-fragments)
// rkB[dir][nt48][kc32][col16][i8] = bf16( rk[kc*8+i][nt*16+col] )
__global__ __launch_bounds__(256) void pack_rkB_kernel(
    const float* __restrict__ rkf, const float* __restrict__ rkb,
    unsigned short* __restrict__ rkB)
{
    const int idx = blockIdx.x * 256 + threadIdx.x;   // < 196608
    const int dir = blockIdx.y;
    const float* rk = dir ? rkb : rkf;
    const int i   = idx & 7;
    const int col = (idx >> 3) & 15;
    const int kc  = (idx >> 7) & 31;
    const int nt  = idx >> 12;         // 0..47
    rkB[dir * RKB_PER_DIR + idx] = f2bf(rk[(kc * 8 + i) * H3 + nt * 16 + col]);
}

// ---------------------------------------------------------------- pack W
// Wp[nt][kc][col][i] = bf16( W[kc*8+i][nt*16+col] ), zero-padded cols.
__global__ __launch_bounds__(256) void pack_W_kernel(
    const float* __restrict__ W, unsigned short* __restrict__ Wp)
{
    const int idx = blockIdx.x * 256 + threadIdx.x;   // < 416*8192
    const int i   = idx & 7;
    const int col = (idx >> 3) & 15;
    const int kc  = (idx >> 7) & 63;
    const int nt  = idx >> 13;
    const int k = kc * 8 + i;
    const int c = nt * 16 + col;
    const float v = (c < C) ? W[k * C + c] : 0.f;
    Wp[idx] = f2bf(v);
}

// ---------------------------------------------------------------- pack xb
// xb[t*32+b][k] = bf16( x[b][t][k] ) -- time-major, coalesced in k.
__global__ __launch_bounds__(256) void pack_xb_kernel(
    const float* __restrict__ x, unsigned short* __restrict__ xb)
{
    const int idx = blockIdx.x * 256 + threadIdx.x;   // < 2,621,440
    const int k   = idx & 511;
    const int row = idx >> 9;          // t*32+b
    const int t   = row >> 5;
    const int b   = row & 31;
    xb[idx] = f2bf(x[(b * T + t) * 512 + k]);
}

// ---------------------------------------------------------------- pack kern
// kernP[dir][nt48][kc64][col16][i8] = bf16( kern[kc*8+i][nt*16+col] )
__global__ __launch_bounds__(256) void pack_kern_kernel(
    const float* __restrict__ kf, const float* __restrict__ kb,
    unsigned short* __restrict__ kernP)
{
    const int idx = blockIdx.x * 256 + threadIdx.x;   // < 393216
    const int dir = blockIdx.y;
    const float* kern = dir ? kb : kf;
    const int i   = idx & 7;
    const int col = (idx >> 3) & 15;
    const int kc  = (idx >> 7) & 63;
    const int nt  = idx >> 13;         // 0..47
    kernP[dir * KP_PER_DIR + idx] = f2bf(kern[(kc * 8 + i) * H3 + nt * 16 + col]);
}

// ---------------------------------------------------------------- K1: proj (MFMA)
// grid (240, 2). Output xpb in BF16 (scan reads it; halves scan HBM bytes).
__global__ __launch_bounds__(256) void proj_mfma_kernel(
    const unsigned short* __restrict__ xb,     // [5120][512] bf16
    const unsigned short* __restrict__ kernP,  // [2][48][64][16][8]
    const float* __restrict__ bias_f,          // [2][H3]
    const float* __restrict__ bias_b,
    unsigned short* __restrict__ xpb)          // [2*5120][768] bf16
{
    const int bid = blockIdx.x;
    const int ct  = bid / 40;          // 0..5
    const int rt  = bid % 40;          // 0..39
    const int dir = blockIdx.y;
    const int lane = threadIdx.x & 63;
    const int wid  = threadIdx.x >> 6;
    const int wm = wid >> 1, wn = wid & 1;
    const int rowBase = rt * 128 + wm * 64;
    const int lrow = lane & 15;
    const int lk8  = lane >> 4;        // 0..3
    const float* bias = dir ? bias_b : bias_f;

    float4v acc[4][4];
#pragma unroll
    for (int i = 0; i < 4; ++i)
#pragma unroll
        for (int k = 0; k < 4; ++k) acc[i][k] = (float4v){0.f, 0.f, 0.f, 0.f};

    const short* A  = (const short*)xb;
    const short* Bp = (const short*)(kernP + dir * KP_PER_DIR);
    const int ntBase = ct * 8 + wn * 4;

    int arow[4];
#pragma unroll
    for (int mt = 0; mt < 4; ++mt) {
        const int r0 = rowBase + mt * 16;
        const int s  = r0 >> 5;
        arow[mt] = (dir ? (159 - s) : s) * 32 + (r0 & 31);
    }

    for (int k0 = 0; k0 < 512; k0 += 32) {
        short8v aF[4], bF[4];
#pragma unroll
        for (int mt = 0; mt < 4; ++mt)
            aF[mt] = *(const short8v*)&A[(arow[mt] + lrow) * 512 + k0 + lk8 * 8];
#pragma unroll
        for (int ntw = 0; ntw < 4; ++ntw)
            bF[ntw] = *(const short8v*)&Bp[((ntBase + ntw) * 64 + (k0 >> 3) + lk8) * 128 + lrow * 8];
#pragma unroll
        for (int mt = 0; mt < 4; ++mt)
#pragma unroll
            for (int ntw = 0; ntw < 4; ++ntw)
                acc[mt][ntw] = __builtin_amdgcn_mfma_f32_16x16x32_bf16(
                    aF[mt], bF[ntw], acc[mt][ntw], 0, 0, 0);
    }

    const int orow = (lane >> 4) * 4;   // C/D: col=lane&15, row=(lane>>4)*4+reg
#pragma unroll
    for (int ntw = 0; ntw < 4; ++ntw) {
        const int c = (ntBase + ntw) * 16 + lrow;   // 0..767
        const float bc = bias[c];
#pragma unroll
        for (int mt = 0; mt < 4; ++mt)
#pragma unroll
            for (int v = 0; v < 4; ++v)
                xpb[(size_t)(dir * 5120 + rowBase + mt * 16 + orow + v) * H3 + c]
                    = f2bf(acc[mt][ntw][v] + bc);
    }
}

// ---------------------------------------------------------------- K2: scan v6 (MFMA)
// grid 64 = (dir<<5)|b, block 768 = 12 waves. Wave w owns gate cols
// [w*64, +64) = 4 n-tiles; B-frags (128 regs) loaded once, AGPR-native for
// MFMA. Per step: A = h row-replicated; result read from row 0.
__global__ __launch_bounds__(768, 3) void gru_scan_v6(
    const unsigned short* __restrict__ xpb, // [2][T][B][H3] bf16
    const unsigned short* __restrict__ rkB, // [2][48][32][16][8]
    const float* __restrict__ bias_f,
    const float* __restrict__ bias_b,
    __hip_bfloat16* __restrict__ hcatb)    // [T][B][2H] bf16
{
    const int bid = blockIdx.x;
    const int dir = bid >> 5;
    const int b   = bid & 31;
    const int tid = threadIdx.x;
    const int wv  = tid >> 6;          // 0..11
    const int lane = tid & 63;
    const int lrow = lane & 15;
    const int lk8  = lane >> 4;        // 0..3
    const int j   = tid & 255;
    const float* bias = dir ? bias_b : bias_f;
    const short* Bp = (const short*)(rkB + (size_t)dir * RKB_PER_DIR);

    short8v bw[32];                    // [nt 0..3][kk 0..7]
#pragma unroll
    for (int i = 0; i < 4; ++i)
#pragma unroll
        for (int kk = 0; kk < 8; ++kk)
            bw[i * 8 + kk] = *(const short8v*)
                &Bp[(((wv * 4 + i) * 32) + kk * 4 + lk8) * 128 + lrow * 8];

    float rbz = 0.f, rbr = 0.f, rbh = 0.f;
    if (tid < 256) {
        rbz = bias[H3 + j];
        rbr = bias[H3 + 256 + j];
        rbh = bias[H3 + 512 + j];
    }

    __shared__ float hfp[256];                         // fp32 h (for z*h_old)
    __shared__ __align__(16) unsigned short hus[256];  // bf16 h (A operand)
    __shared__ float sums[768];                        // gate dots
    if (tid < 256) { hfp[tid] = 0.f; hus[tid] = 0; }
    __syncthreads();

    for (int s = 0; s < T; ++s) {
        float xz = 0.f, xr = 0.f, xh = 0.f;
        if (tid < 256) {               // issue early; hides under MFMA phase
            const unsigned short* xrow = xpb + ((size_t)(dir * T + s) * B + b) * H3;
            xz = bf2f(xrow[j]);
            xr = bf2f(xrow[256 + j]);
            xh = bf2f(xrow[512 + j]);
        }

        float4v a0 = {0.f,0.f,0.f,0.f}, a1 = {0.f,0.f,0.f,0.f};
        float4v a2 = {0.f,0.f,0.f,0.f}, a3 = {0.f,0.f,0.f,0.f};
#pragma unroll
        for (int kk = 0; kk < 8; ++kk) {
            short8v aF = *(const short8v*)&hus[kk * 32 + lk8 * 8];  // broadcast
            a0 = __builtin_amdgcn_mfma_f32_16x16x32_bf16(aF, bw[0 * 8 + kk], a0, 0, 0, 0);
            a1 = __builtin_amdgcn_mfma_f32_16x16x32_bf16(aF, bw[1 * 8 + kk], a1, 0, 0, 0);
            a2 = __builtin_amdgcn_mfma_f32_16x16x32_bf16(aF, bw[2 * 8 + kk], a2, 0, 0, 0);
            a3 = __builtin_amdgcn_mfma_f32_16x16x32_bf16(aF, bw[3 * 8 + kk], a3, 0, 0, 0);
        }
        if (lane < 16) {               // row 0 = lanes 0..15, reg 0
            sums[(wv * 4 + 0) * 16 + lane] = a0[0];
            sums[(wv * 4 + 1) * 16 + lane] = a1[0];
            sums[(wv * 4 + 2) * 16 + lane] = a2[0];
            sums[(wv * 4 + 3) * 16 + lane] = a3[0];
        }
        __syncthreads();               // sums visible

        if (tid < 256) {
            const float sz = sums[j];
            const float sr = sums[256 + j];
            const float sh = sums[512 + j];
            const float z  = 1.f / (1.f + __expf(-(xz + sz + rbz)));
            const float r  = 1.f / (1.f + __expf(-(xr + sr + rbr)));
            const float pre = xh + r * (sh + rbh);
            const float e2  = __expf(2.f * pre);
            const float hh  = 1.f - 2.f / (e2 + 1.f);   // tanh, inf-safe
            const float hn  = z * hfp[j] + (1.f - z) * hh;
            hfp[j] = hn;
            hus[j] = f2bf(hn);
            const int ta = dir ? (T - 1 - s) : s;
            hcatb[(ta * B + b) * 512 + dir * 256 + j] = __float2bfloat16(hn);
        }
        __syncthreads();               // h_{s+1} ready
    }
}

// ---------------------------------------------------------------- K3: cls v2 (MFMA, LDS A)
// grid 1040 = 26 ctn x 40 rt, ct-major (256-col W slice = 256 KB L2-resident).
// Block 128 rows x 256 cols, 4 waves 2x2 -> wave 64x128 (mt=4, nt=8).
// A staged once in 128 KB LDS, XOR-swizzled: byte ^= (row&7)<<4 (else the
// 1024-B row stride makes the 16-lane frag read a 16-way bank conflict).
__global__ __launch_bounds__(256) void cls_mfma2_kernel(
    const unsigned short* __restrict__ hcatb,  // [5120][512] bf16
    const unsigned short* __restrict__ Wp,     // [416][64][16][8]
    const float* __restrict__ bias,
    float* __restrict__ out)
{
    const int bid = blockIdx.x;
    const int ctn = bid / 40;          // 0..25
    const int rt  = bid % 40;          // 0..39
    const int tid = threadIdx.x;
    const int lane = tid & 63;
    const int wid  = tid >> 6;
    const int wm = wid >> 1, wn = wid & 1;
    const int lrow = lane & 15;
    const int lk8  = lane >> 4;        // 0..3
    const int r0   = rt * 128;

    __shared__ __align__(16) unsigned short As[128 * 512];   // 128 KB swizzled

    {   // stage 128x512 bf16: 32 x 16B chunks per thread, coalesced global
        const uint4* src = (const uint4*)hcatb;    // row = 64 uint4
        for (int it = 0; it < 32; ++it) {
            const int v   = it * 256 + tid;        // 0..8191
            const int row = v >> 6;
            const int c16 = (v & 63) << 4;         // byte offset in row
            const uint4 d = src[(size_t)(r0 + row) * 64 + (v & 63)];
            *(uint4*)((char*)As + row * 1024 + (c16 ^ ((row & 7) << 4))) = d;
        }
    }
    __syncthreads();

    float4v acc[4][8];
#pragma unroll
    for (int i = 0; i < 4; ++i)
#pragma unroll
        for (int k = 0; k < 8; ++k) acc[i][k] = (float4v){0.f, 0.f, 0.f, 0.f};

    const short* Bp = (const short*)Wp;
    const int ntBase = ctn * 16 + wn * 8;

    for (int k0 = 0; k0 < 512; k0 += 32) {
        short8v aF[4], bF[8];
#pragma unroll
        for (int mt = 0; mt < 4; ++mt) {
            const int row = wm * 64 + mt * 16 + lrow;
            const int cb  = (k0 * 2 + lk8 * 16) ^ ((row & 7) << 4);
            aF[mt] = *(const short8v*)((const char*)As + row * 1024 + cb);
        }
#pragma unroll
        for (int ntw = 0; ntw < 8; ++ntw)
            bF[ntw] = *(const short8v*)&Bp[((ntBase + ntw) * 64 + (k0 >> 3) + lk8) * 128 + lrow * 8];
#pragma unroll
        for (int mt = 0; mt < 4; ++mt)
#pragma unroll
            for (int ntw = 0; ntw < 8; ++ntw)
                acc[mt][ntw] = __builtin_amdgcn_mfma_f32_16x16x32_bf16(
                    aF[mt], bF[ntw], acc[mt][ntw], 0, 0, 0);
    }

    const int orow = (lane >> 4) * 4;   // C/D: col=lane&15, row=(lane>>4)*4+reg
#pragma unroll
    for (int ntw = 0; ntw < 8; ++ntw) {
        const int c = (ntBase + ntw) * 16 + lrow;
        if (c >= C) continue;
        const float bc = bias[c];
#pragma unroll
        for (int mt = 0; mt < 4; ++mt)
#pragma unroll
            for (int v = 0; v < 4; ++v)
                out[(size_t)(r0 + wm * 64 + mt * 16 + orow + v) * C + c]
                    = acc[mt][ntw][v] + bc;
    }
}

// ============================ fallback fp32 path (small ws) ============================
__global__ __launch_bounds__(256) void proj_kernel(
    const float* __restrict__ x, const float* __restrict__ kf,
    const float* __restrict__ kb, const float* __restrict__ bias_f,
    const float* __restrict__ bias_b, float* __restrict__ xp)
{
    const int ct  = blockIdx.x;
    const int s   = blockIdx.y;
    const int dir = blockIdx.z;
    const int tid = threadIdx.x;
    const int t   = dir ? (T - 1 - s) : s;
    const float* kern = dir ? kb : kf;
    const float* bias = dir ? bias_b : bias_f;

    __shared__ float xs[32 * 512];
    for (int it = 0; it < 16; ++it) {
        int v = it * 256 + tid, row = v >> 7, k4 = v & 127;
        *(float4*)&xs[(row << 9) + (k4 << 2)] =
            *(const float4*)&x[((row * T + t) << 9) + (k4 << 2)];
    }
    __syncthreads();

    const int col = ct * 256 + tid;
    float acc[32];
#pragma unroll
    for (int r = 0; r < 32; ++r) acc[r] = 0.f;
    for (int k = 0; k < 512; k += 4) {
        float w0 = kern[(k + 0) * H3 + col];
        float w1 = kern[(k + 1) * H3 + col];
        float w2 = kern[(k + 2) * H3 + col];
        float w3 = kern[(k + 3) * H3 + col];
#pragma unroll
        for (int r = 0; r < 32; ++r) {
            float4 xv = *(const float4*)&xs[(r << 9) + k];
            acc[r] += xv.x * w0 + xv.y * w1 + xv.z * w2 + xv.w * w3;
        }
    }
    const float bb = bias[col];
    for (int r = 0; r < 32; ++r)
        xp[((dir * T + s) * B + r) * H3 + col] = acc[r] + bb;
}

__global__ __launch_bounds__(1024) void gru_scan_f32(
    const float* __restrict__ xp,
    const float* __restrict__ rk_f, const float* __restrict__ rk_b,
    const float* __restrict__ bias_f, const float* __restrict__ bias_b,
    float* __restrict__ hcat)
{
    const int bid = blockIdx.x;
    const int dir = bid >> 5;
    const int b   = bid & 31;
    const int tid = threadIdx.x;
    const int kg  = tid >> 8;
    const int j   = tid & 255;
    const int k0  = kg << 6;
    const float* rk   = dir ? rk_b : rk_f;
    const float* bias = dir ? bias_b : bias_f;
    const float rbz = bias[H3 + j];
    const float rbr = bias[H3 + 256 + j];
    const float rbh = bias[H3 + 512 + j];

    __shared__ float h[256];
    __shared__ float part[3][4][256];
    if (tid < 256) h[tid] = 0.f;
    __syncthreads();

    for (int s = 0; s < T; ++s) {
        const float* xrow = xp + ((dir * T + s) * B + b) * H3;
        float az = 0.f, ar = 0.f, ah = 0.f;
#pragma unroll 4
        for (int k = k0; k < k0 + 64; k += 4) {
            float4 h4 = *(const float4*)&h[k];
            const float* rkp = rk + k * H3 + j;
            az += h4.x * rkp[0];       ar += h4.x * rkp[256];       ah += h4.x * rkp[512];
            az += h4.y * rkp[H3];      ar += h4.y * rkp[H3+256];    ah += h4.y * rkp[H3+512];
            az += h4.z * rkp[2*H3];    ar += h4.z * rkp[2*H3+256];  ah += h4.z * rkp[2*H3+512];
            az += h4.w * rkp[3*H3];    ar += h4.w * rkp[3*H3+256];  ah += h4.w * rkp[3*H3+512];
        }
        part[0][kg][j] = az; part[1][kg][j] = ar; part[2][kg][j] = ah;
        __syncthreads();
        if (tid < 256) {
            const float sz = part[0][0][tid]+part[0][1][tid]+part[0][2][tid]+part[0][3][tid];
            const float sr = part[1][0][tid]+part[1][1][tid]+part[1][2][tid]+part[1][3][tid];
            const float sh = part[2][0][tid]+part[2][1][tid]+part[2][2][tid]+part[2][3][tid];
            const float xz = xrow[tid], xr = xrow[256+tid], xh = xrow[512+tid];
            const float z  = 1.f / (1.f + __expf(-(xz + sz + rbz)));
            const float r  = 1.f / (1.f + __expf(-(xr + sr + rbr)));
            const float pre = xh + r * (sh + rbh);
            const float e2  = __expf(2.f * pre);
            const float hh  = 1.f - 2.f / (e2 + 1.f);
            const float hn  = z * h[tid] + (1.f - z) * hh;
            h[tid] = hn;
            const int ta = dir ? (T - 1 - s) : s;
            hcat[(ta * B + b) * (2 * H) + dir * H + tid] = hn;
        }
        __syncthreads();
    }
}

__global__ __launch_bounds__(256) void cls_f32_kernel(
    const float* __restrict__ hcat, const float* __restrict__ W,
    const float* __restrict__ bias, float* __restrict__ out)
{
    const int bid = blockIdx.x;
    const int ct  = bid / 160;
    const int rt  = bid % 160;
    const int tid = threadIdx.x;
    const int r0  = rt * 32;

    __shared__ float hs[32 * 512];
    for (int it = 0; it < 16; ++it) {
        int v = it * 256 + tid, row = v >> 7, k4 = v & 127;
        *(float4*)&hs[(row << 9) + (k4 << 2)] =
            *(const float4*)&hcat[((r0 + row) << 9) + (k4 << 2)];
    }
    __syncthreads();

    const int c0 = ct * 512 + tid;
    const int c1 = c0 + 256;
    const bool v1 = (c1 < C);
    float acc0[32], acc1[32];
#pragma unroll
    for (int r = 0; r < 32; ++r) { acc0[r] = 0.f; acc1[r] = 0.f; }
    for (int k = 0; k < 512; k += 4) {
        const float* wp = W + k * C;
        float w00 = wp[c0], w01 = wp[C+c0], w02 = wp[2*C+c0], w03 = wp[3*C+c0];
        float w10 = v1 ? wp[c1] : 0.f, w11 = v1 ? wp[C+c1] : 0.f;
        float w12 = v1 ? wp[2*C+c1] : 0.f, w13 = v1 ? wp[3*C+c1] : 0.f;
#pragma unroll
        for (int r = 0; r < 32; ++r) {
            float4 hv = *(const float4*)&hs[(r << 9) + k];
            acc0[r] += hv.x*w00 + hv.y*w01 + hv.z*w02 + hv.w*w03;
            acc1[r] += hv.x*w10 + hv.y*w11 + hv.z*w12 + hv.w*w13;
        }
    }
    const float b0 = bias[c0];
    const float b1 = v1 ? bias[c1] : 0.f;
    for (int r = 0; r < 32; ++r) {
        out[(size_t)(r0+r)*C + c0] = acc0[r] + b0;
        if (v1) out[(size_t)(r0+r)*C + c1] = acc1[r] + b1;
    }
}

// ---------------------------------------------------------------- launch
extern "C" void kernel_launch(void* const* d_in, const int* in_sizes, int n_in,
                              void* d_out, int out_size, void* d_ws, size_t ws_size,
                              hipStream_t stream) {
    const float* x     = (const float*)d_in[0];
    const float* kf    = (const float*)d_in[1];
    const float* rkf   = (const float*)d_in[2];
    const float* biasf = (const float*)d_in[3];
    const float* kb    = (const float*)d_in[4];
    const float* rkb   = (const float*)d_in[5];
    const float* biasb = (const float*)d_in[6];
    const float* W     = (const float*)d_in[7];
    const float* bvec  = (const float*)d_in[8];
    float* out = (float*)d_out;

    const size_t rkB_bytes   = (size_t)2 * RKB_PER_DIR * 2;       //   786,432
    const size_t Wp_bytes    = (size_t)NT16 * 8192 * 2;           // 6,815,744
    const size_t hcatb_bytes = (size_t)T * B * 2 * H * 2;         // 5,242,880
    const size_t planA_bytes = rkB_bytes + Wp_bytes + hcatb_bytes;

    // d_out (135.7 MB) carved up; all regions dead before cls writes out:
    //   [0, 15.7 MB)        xpb   [2*5120][768] bf16
    //   [31.5, 36.7 MB)     xb    [5120][512] bf16   (offsets kept from R7)
    //   [36.7, 38.3 MB)     kernP [2][393216] bf16
    unsigned short* xpb   = (unsigned short*)out;
    unsigned short* xb    = (unsigned short*)((char*)out + (size_t)2 * 5120 * H3 * 4);
    unsigned short* kernP = (unsigned short*)((char*)xb + (size_t)5120 * 512 * 2);

    if (ws_size >= planA_bytes) {
        char* wsb = (char*)d_ws;
        unsigned short* rkB   = (unsigned short*)wsb;
        unsigned short* Wp    = (unsigned short*)(wsb + rkB_bytes);
        __hip_bfloat16* hcatb = (__hip_bfloat16*)(wsb + rkB_bytes + Wp_bytes);

        pack_rkB_kernel<<<dim3(768, 2), 256, 0, stream>>>(rkf, rkb, rkB);
        pack_W_kernel<<<13312, 256, 0, stream>>>(W, Wp);
        pack_xb_kernel<<<10240, 256, 0, stream>>>(x, xb);
        pack_kern_kernel<<<dim3(1536, 2), 256, 0, stream>>>(kf, kb, kernP);

        proj_mfma_kernel<<<dim3(240, 2), 256, 0, stream>>>(xb, kernP, biasf, biasb, xpb);

        gru_scan_v6<<<64, 768, 0, stream>>>(xpb, rkB, biasf, biasb, hcatb);

        cls_mfma2_kernel<<<1040, 256, 0, stream>>>((const unsigned short*)hcatb,
                                                   Wp, bvec, out);
    } else {
        // fp32 fallback (round-2 path)
        float* xp   = out;
        float* hcat = (float*)d_ws;     // 10.5 MB
        dim3 g1(3, T, 2);
        proj_kernel<<<g1, 256, 0, stream>>>(x, kf, kb, biasf, biasb, xp);
        gru_scan_f32<<<64, 1024, 0, stream>>>(xp, rkf, rkb, biasf, biasb, hcat);
        cls_f32_kernel<<<13 * 160, 256, 0, stream>>>(hcat, W, bvec, out);
    }
}